// Round 1
// baseline (404.149 us; speedup 1.0000x reference)
//
#include <hip/hip_runtime.h>
#include <stdint.h>

typedef unsigned short u16;
typedef __attribute__((ext_vector_type(8))) short short8x;   // 8 x bf16 (4 VGPRs)
typedef __attribute__((ext_vector_type(4))) float floatx4;   // MFMA C/D

#define TOKENS 2048   // B*T
#define EMBED  4096
#define QKVN   6144   // 4096 q + 1024 k + 1024 v
#define T_SEQ  1024
#define SMAX   2048   // cache length (2*KV_SEQ_LEN)
#define NQH    32
#define NKVH   8
#define HD     128

// RNE f32 -> bf16 (finite inputs only)
static __device__ __forceinline__ u16 f2b(float f) {
    union { float f; uint32_t u; } v; v.f = f;
    uint32_t r = v.u + 0x7fffu + ((v.u >> 16) & 1u);
    return (u16)(r >> 16);
}
static __device__ __forceinline__ float b2f(u16 h) {
    union { uint32_t u; float f; } v; v.u = ((uint32_t)h) << 16; return v.f;
}

static __device__ __forceinline__ void gload_lds16(const u16* g, u16* l) {
    __builtin_amdgcn_global_load_lds(
        (const __attribute__((address_space(1))) uint32_t*)g,
        (__attribute__((address_space(3))) uint32_t*)l, 16, 0, 0);
}

// ---------------- fused f32 -> bf16 conversion for all 5 inputs ----------------
#define CSEG0 2097152              // x        (2048*4096/4)
#define CSEG1 6291456              // +Wq      (4096*4096/4)
#define CSEG2 7340032              // +Wk      (1024*4096/4)
#define CSEG3 8388608              // +Wv      (1024*4096/4)
#define CSEG4 12582912             // +Wo      (4096*4096/4)
__global__ void convert_all_kernel(const float* __restrict__ x,  const float* __restrict__ Wq,
                                   const float* __restrict__ Wk, const float* __restrict__ Wv,
                                   const float* __restrict__ Wo,
                                   u16* __restrict__ xb, u16* __restrict__ wqkv,
                                   u16* __restrict__ wob) {
    int i = blockIdx.x * blockDim.x + threadIdx.x;   // float4 index
    if (i >= CSEG4) return;
    const float4* src; uint2* dst; int off;
    if (i < CSEG0)      { src = (const float4*)x;  dst = (uint2*)xb;   off = i; }
    else if (i < CSEG1) { src = (const float4*)Wq; dst = (uint2*)wqkv; off = i - CSEG0; }
    else if (i < CSEG2) { src = (const float4*)Wk; dst = (uint2*)wqkv + 4194304; off = i - CSEG1; }
    else if (i < CSEG3) { src = (const float4*)Wv; dst = (uint2*)wqkv + 5242880; off = i - CSEG2; }
    else                { src = (const float4*)Wo; dst = (uint2*)wob;  off = i - CSEG3; }
    float4 f = src[off];
    union { u16 h[4]; uint2 v; } o;
    o.h[0] = f2b(f.x); o.h[1] = f2b(f.y); o.h[2] = f2b(f.z); o.h[3] = f2b(f.w);
    dst[off] = o.v;
}

// ---------------- bf16 GEMM: C[M,N] = A[M,K] * B[N,K]^T ----------------
// 256x256 tile, BK=64, 8 waves (2M x 4N), 8-phase K-loop with counted vmcnt
// (m201/HK-style schedule). LDS: 2 bufs x {A,B} x 2 halves x [128 rows x 64 cols].
// Swizzle: logical (row, slot) stored at slot^(row&7) -> conflict-free ds_read_b128;
// global_load_lds dest stays linear, the per-lane GLOBAL source is pre-swizzled
// (both-sides-or-neither, rule 21). Per-tile phases consume quadrants
// p1(A0,B0) p2(A0,B1) p3(A1,B1) p4(A1,B0), so half-tile slots free mid-tile:
//   issue A1/B0(T+1)@T.p1, A0(T+2)@T.p3, B1(T+2)@T.p4  =>  boundary wait vmcnt(4).
#define HB(BUF, MAT, H) (lds + (((BUF) * 4 + (MAT) * 2 + (H)) * 8192))
#define STAGE(BUF, MAT, H, KT) do { \
    const u16* _g0 = (MAT) ? gB[H][0] : gA[H][0]; \
    const u16* _g1 = (MAT) ? gB[H][1] : gA[H][1]; \
    gload_lds16(_g0 + (size_t)(KT) * 64, HB(BUF, MAT, H) + dOff0); \
    gload_lds16(_g1 + (size_t)(KT) * 64, HB(BUF, MAT, H) + dOff1); \
} while (0)
#define WAIT4 asm volatile("s_waitcnt vmcnt(4)" ::: "memory")
#define WAIT0 asm volatile("s_waitcnt vmcnt(0)" ::: "memory")
#define NOSTG ((void)0)
#define PHASE(CBUF, AH, BH, STAGES, ENDW) do { \
    const u16* _pA = HB(CBUF, 0, AH); \
    const u16* _pB = HB(CBUF, 1, BH); \
    short8x _af[4][2], _bf[2][2]; \
    _Pragma("unroll") \
    for (int _mi = 0; _mi < 4; _mi++) { \
        _af[_mi][0] = *(const short8x*)(_pA + offA[_mi][0]); \
        _af[_mi][1] = *(const short8x*)(_pA + offA[_mi][1]); \
    } \
    _Pragma("unroll") \
    for (int _ni = 0; _ni < 2; _ni++) { \
        _bf[_ni][0] = *(const short8x*)(_pB + offB[_ni][0]); \
        _bf[_ni][1] = *(const short8x*)(_pB + offB[_ni][1]); \
    } \
    STAGES; \
    __builtin_amdgcn_s_barrier(); \
    asm volatile("s_waitcnt lgkmcnt(0)" ::: "memory"); \
    __builtin_amdgcn_sched_barrier(0); \
    __builtin_amdgcn_s_setprio(1); \
    _Pragma("unroll") \
    for (int _kk = 0; _kk < 2; _kk++) \
        _Pragma("unroll") \
        for (int _mi = 0; _mi < 4; _mi++) \
            _Pragma("unroll") \
            for (int _ni = 0; _ni < 2; _ni++) \
                acc[AH][BH][_mi][_ni] = __builtin_amdgcn_mfma_f32_16x16x32_bf16( \
                    _af[_mi][_kk], _bf[_ni][_kk], acc[AH][BH][_mi][_ni], 0, 0, 0); \
    __builtin_amdgcn_s_setprio(0); \
    ENDW; \
    __builtin_amdgcn_s_barrier(); \
    __builtin_amdgcn_sched_barrier(0); \
} while (0)

template <bool BF16OUT>
__global__ __launch_bounds__(512, 2) void gemm256_kernel(
    const u16* __restrict__ A, const u16* __restrict__ Bw,
    void* __restrict__ Cv, int N, int K) {
    extern __shared__ __align__(16) u16 lds[];   // 128 KiB dynamic
    const int tid = threadIdx.x;
    const int lane = tid & 63, w = tid >> 6;
    const int quad = lane >> 4, lc = lane & 15;
    const int wm = w >> 2, wn = w & 3;           // 2M x 4N wave grid
    const int Mbase = blockIdx.y * 256, Nbase = blockIdx.x * 256;

    // ---- staging addresses: linear LDS dest, swizzled global source ----
    const int r8 = lane >> 3;                    // row within 8-row wave stripe
    const int sl = (lane & 7) ^ r8;              // pre-swizzled 16B slot in row
    const int srow = w * 8 + r8;                 // 0..63 within a 64-row load stripe
    const u16* gA[2][2];                         // [half][load]
    const u16* gB[2][2];
#pragma unroll
    for (int H = 0; H < 2; H++)
#pragma unroll
        for (int L = 0; L < 2; L++) {
            gA[H][L] = A  + (size_t)(Mbase + H * 128 + L * 64 + srow) * K + sl * 8;
            gB[H][L] = Bw + (size_t)(Nbase + H * 128 + L * 64 + srow) * K + sl * 8;
        }
    const int dOff0 = w * 8 * 64;                // wave-uniform LDS dests (u16)
    const int dOff1 = (64 + w * 8) * 64;

    // ---- ds_read offsets (u16) within a 128x64 half-buffer, swizzled ----
    int offA[4][2], offB[2][2];
    const int xsw = lc & 7;
#pragma unroll
    for (int mi = 0; mi < 4; mi++)
#pragma unroll
        for (int kk = 0; kk < 2; kk++)
            offA[mi][kk] = (wm * 64 + mi * 16 + lc) * 64 + (((kk * 4 + quad) ^ xsw) * 8);
#pragma unroll
    for (int ni = 0; ni < 2; ni++)
#pragma unroll
        for (int kk = 0; kk < 2; kk++)
            offB[ni][kk] = (wn * 32 + ni * 16 + lc) * 64 + (((kk * 4 + quad) ^ xsw) * 8);

    floatx4 acc[2][2][4][2] = {};                // [AH][BH][mi][ni]

    // prologue: all of tile 0, then A0(1),B1(1); wait leaves only those 4 in flight
    STAGE(0, 0, 0, 0);
    STAGE(0, 1, 0, 0);
    STAGE(0, 1, 1, 0);
    STAGE(0, 0, 1, 0);
    STAGE(1, 0, 0, 1);
    STAGE(1, 1, 1, 1);
    WAIT4;
    __builtin_amdgcn_s_barrier();
    __builtin_amdgcn_sched_barrier(0);

    const int NT = K >> 6;                       // 64 for K=4096 (even)
    for (int t = 0; t < NT - 2; t += 2) {
        // tile t (buf 0)
        PHASE(0, 0, 0, STAGE(1, 0, 1, t + 1); STAGE(1, 1, 0, t + 1), NOSTG);
        PHASE(0, 0, 1, NOSTG, NOSTG);
        PHASE(0, 1, 1, STAGE(0, 0, 0, t + 2), NOSTG);
        PHASE(0, 1, 0, STAGE(0, 1, 1, t + 2), WAIT4);
        // tile t+1 (buf 1)
        PHASE(1, 0, 0, STAGE(0, 0, 1, t + 2); STAGE(0, 1, 0, t + 2), NOSTG);
        PHASE(1, 0, 1, NOSTG, NOSTG);
        PHASE(1, 1, 1, STAGE(1, 0, 0, t + 3), NOSTG);
        PHASE(1, 1, 0, STAGE(1, 1, 1, t + 3), WAIT4);
    }
    // tile NT-2 (buf 0): finish staging tile NT-1, then drain fully
    PHASE(0, 0, 0, STAGE(1, 0, 1, NT - 1); STAGE(1, 1, 0, NT - 1), NOSTG);
    PHASE(0, 0, 1, NOSTG, NOSTG);
    PHASE(0, 1, 1, NOSTG, NOSTG);
    PHASE(0, 1, 0, NOSTG, WAIT0);
    // tile NT-1 (buf 1)
    PHASE(1, 0, 0, NOSTG, NOSTG);
    PHASE(1, 0, 1, NOSTG, NOSTG);
    PHASE(1, 1, 1, NOSTG, NOSTG);
    PHASE(1, 1, 0, NOSTG, NOSTG);

    // epilogue C write (C/D layout: col = lane&15, row = quad*4 + r)
#pragma unroll
    for (int AH = 0; AH < 2; AH++)
#pragma unroll
        for (int mi = 0; mi < 4; mi++) {
            const int row0 = Mbase + AH * 128 + wm * 64 + mi * 16 + quad * 4;
#pragma unroll
            for (int BH = 0; BH < 2; BH++)
#pragma unroll
                for (int ni = 0; ni < 2; ni++) {
                    const int col = Nbase + BH * 128 + wn * 32 + ni * 16 + lc;
#pragma unroll
                    for (int r = 0; r < 4; r++) {
                        if constexpr (BF16OUT)
                            ((u16*)Cv)[(size_t)(row0 + r) * N + col] = f2b(acc[AH][BH][mi][ni][r]);
                        else
                            ((float*)Cv)[(size_t)(row0 + r) * N + col] = acc[AH][BH][mi][ni][r];
                    }
                }
        }
}
#undef HB
#undef STAGE
#undef WAIT4
#undef WAIT0
#undef NOSTG
#undef PHASE

// ---------------- cache prefix copy (no-op when start_pos==0) ----------------
// kh: (b,g,s,d) row-major. vt8: 8-token interleaved (s>>3)*1024 + d*8 + (s&7).
__global__ void cache_prefix_kernel(const float* __restrict__ ck, const float* __restrict__ cv,
                                    const int* __restrict__ sp,
                                    u16* __restrict__ kh, u16* __restrict__ vt8) {
    int spos = sp[0];
    long total = (long)2 * spos * NKVH * HD;
    for (long i = (long)blockIdx.x * blockDim.x + threadIdx.x; i < total; i += (long)gridDim.x * blockDim.x) {
        long d = i % HD, rest = i / HD;
        long g = rest % NKVH; rest /= NKVH;
        long s = rest % spos; long b = rest / spos;
        float kv = ck[((b * SMAX + s) * NKVH + g) * HD + d];
        kh[((b * NKVH + g) * SMAX + s) * HD + d] = f2b(kv);
        float vv = cv[((b * SMAX + s) * NKVH + g) * HD + d];
        vt8[(size_t)(b * NKVH + g) * SMAX * HD + (s >> 3) * 1024 + d * 8 + (s & 7)] = f2b(vv);
    }
}

// ---------------- RoPE for Q and K (reads bf16 qkv) ----------------
__global__ void rope_qk_kernel(const u16* __restrict__ qkvb, const int* __restrict__ sp,
                               u16* __restrict__ qh, u16* __restrict__ kh) {
    int spos = sp[0];
    int idx = blockIdx.x * blockDim.x + threadIdx.x;   // tok*2560 + u
    int tok = idx / 2560;
    int u = idx - tok * 2560;
    int b = tok >> 10, t = tok & 1023;
    float pos = (float)(spos + t);
    const u16* src = qkvb + (size_t)tok * QKVN;
    const float kScale = 0.08838834764831845f;  // 1/sqrt(128)
    const float kLog = -0.20762050593045857f;   // -log2(10000)/64
    if (u < 2048) {                 // q: 32 heads x 64 pairs
        int h = u >> 6, i = u & 63;
        float ang = pos * exp2f((float)i * kLog);
        float cs = cosf(ang), sn = sinf(ang);
        float x0 = b2f(src[h * HD + 2 * i]), x1 = b2f(src[h * HD + 2 * i + 1]);
        size_t dst = (((size_t)(b * NQH + h) * T_SEQ) + t) * HD + 2 * i;
        qh[dst]     = f2b((x0 * cs - x1 * sn) * kScale);
        qh[dst + 1] = f2b((x0 * sn + x1 * cs) * kScale);
    } else {                        // k: 8 heads x 64 pairs
        int u2 = u - 2048;
        int g = u2 >> 6, i = u2 & 63;
        float ang = pos * exp2f((float)i * kLog);
        float cs = cosf(ang), sn = sinf(ang);
        float x0 = b2f(src[EMBED + g * HD + 2 * i]), x1 = b2f(src[EMBED + g * HD + 2 * i + 1]);
        size_t dst = (((size_t)(b * NKVH + g) * SMAX) + spos + t) * HD + 2 * i;
        kh[dst]     = f2b(x0 * cs - x1 * sn);
        kh[dst + 1] = f2b(x0 * sn + x1 * cs);
    }
}

// ---------------- V pack: bf16 qkv -> 8-token-interleaved vt8 (LDS transpose) ----------------
// Block: one (b, g, 16-token tile). Coalesced reads (256B rows) and writes (1KB waves).
__global__ __launch_bounds__(256) void vpack_kernel(const u16* __restrict__ qkvb,
                                                    const int* __restrict__ sp,
                                                    u16* __restrict__ vt8) {
    __shared__ u16 lds[16 * 136];
    int spos = sp[0];
    int tile = blockIdx.x;          // b*512 + g*64 + t16
    int t16 = tile & 63;
    int g = (tile >> 6) & 7;
    int b = tile >> 9;
    int tok0 = t16 * 16;
    int tid = threadIdx.x;
    {
        int srow = tid >> 4, dc8 = (tid & 15) * 8;
        const u16* src = qkvb + (size_t)(b * T_SEQ + tok0 + srow) * QKVN + 5120 + g * HD + dc8;
        *(uint4*)(lds + srow * 136 + dc8) = *(const uint4*)src;
    }
    __syncthreads();
    int d = tid & 127, half = tid >> 7;
    u16* vpg = vt8 + (size_t)(b * NKVH + g) * SMAX * HD;
    int s0 = spos + tok0;
    u16 val[8];
#pragma unroll
    for (int k = 0; k < 8; k++) val[k] = lds[(half * 8 + k) * 136 + d];
    if ((s0 & 7) == 0) {
        union { u16 h[8]; uint4 u; } pk;
#pragma unroll
        for (int k = 0; k < 8; k++) pk.h[k] = val[k];
        *(uint4*)(vpg + (size_t)((s0 >> 3) + half) * 1024 + d * 8) = pk.u;
    } else {
#pragma unroll
        for (int k = 0; k < 8; k++) {
            int s = s0 + half * 8 + k;
            vpg[(size_t)(s >> 3) * 1024 + d * 8 + (s & 7)] = val[k];
        }
    }
}

// ---------------- causal GQA flash attention v4 ----------------
// Wave M=64 rows = 4 Q-heads (one KV group) x 16 tokens. Block = 4 waves on one
// (b,g,16-token tile), 4-way round-robin key split, fp32 LDS combine. Fixed
// softmax max (m=0); row-sum via ones-B MFMA. V in 8-token-interleaved layout.
// Long causal tiles dispatch first (j reversed) to shrink the tail.
__global__ __launch_bounds__(256, 2) void attn_kernel(
    const u16* __restrict__ qh, const u16* __restrict__ kh,
    const u16* __restrict__ vt8, const int* __restrict__ sp,
    u16* __restrict__ ctx) {
    extern __shared__ __align__(16) char smem[];
    int spos = sp[0];
    int tid = threadIdx.x, w = tid >> 6, lane = tid & 63;
    int quad = lane >> 4, lc = lane & 15;
    int tile = blockIdx.x;          // b*512 + g*64 + (63-j)
    int j = 63 - (tile & 63);       // longest-first dispatch
    int g = (tile >> 6) & 7;
    int b = tile >> 9;
    int qbase = j * 16;

    const u16* kp = kh + (size_t)(b * NKVH + g) * SMAX * HD;
    const u16* vp = vt8 + (size_t)(b * NKVH + g) * SMAX * HD;

    short8x qf[4][4];
#pragma unroll
    for (int m = 0; m < 4; m++) {
        const u16* qp = qh + ((size_t)(b * NQH + g * 4 + m) * T_SEQ + qbase + lc) * HD + quad * 8;
#pragma unroll
        for (int dc = 0; dc < 4; dc++)
            qf[m][dc] = *(const short8x*)(qp + dc * 32);
    }
    short8x ones;
#pragma unroll
    for (int jj = 0; jj < 8; jj++) ones[jj] = (short)0x3F80;   // bf16 1.0

    floatx4 o[4][8] = {};
    floatx4 lacc[4] = {};
    int rowpos = spos + qbase + quad * 4;      // +r = absolute query position
    int nch = (spos + qbase + 16 + 63) >> 6;   // 64-key chunks
    u16* pw = (u16*)smem + w * 4608;           // this wave's P buffer (4 tiles x 16x72)

    for (int c = w; c < nch; c += 4) {
        int koff = c * 64;
#pragma unroll
        for (int st = 0; st < 4; st++) {
            const u16* kr = kp + (size_t)(koff + st * 16 + lc) * HD + quad * 8;
            floatx4 sc[4] = {};
#pragma unroll
            for (int dc = 0; dc < 4; dc++) {
                short8x kf = *(const short8x*)(kr + dc * 32);
#pragma unroll
                for (int m = 0; m < 4; m++)
                    sc[m] = __builtin_amdgcn_mfma_f32_16x16x32_bf16(qf[m][dc], kf, sc[m], 0, 0, 0);
            }
            int skey = koff + st * 16 + lc;
#pragma unroll
            for (int m = 0; m < 4; m++)
#pragma unroll
                for (int r = 0; r < 4; r++) {
                    float p = (skey <= rowpos + r) ? __expf(sc[m][r]) : 0.0f;
                    pw[m * 1152 + (quad * 4 + r) * 72 + st * 16 + lc] = f2b(p);
                }
        }
        asm volatile("s_waitcnt lgkmcnt(0)" ::: "memory");
#pragma unroll
        for (int hf = 0; hf < 2; hf++) {
            short8x pf[4];
#pragma unroll
            for (int m = 0; m < 4; m++)
                pf[m] = *(const short8x*)(pw + m * 1152 + lc * 72 + hf * 32 + quad * 8);
#pragma unroll
            for (int m = 0; m < 4; m++)
                lacc[m] = __builtin_amdgcn_mfma_f32_16x16x32_bf16(pf[m], ones, lacc[m], 0, 0, 0);
            const u16* vbase = vp + ((size_t)koff << 7) + (size_t)(hf * 4 + quad) * 1024 + lc * 8;
#pragma unroll
            for (int dc8 = 0; dc8 < 8; dc8++) {
                short8x vf = *(const short8x*)(vbase + dc8 * 128);
#pragma unroll
                for (int m = 0; m < 4; m++)
                    o[m][dc8] = __builtin_amdgcn_mfma_f32_16x16x32_bf16(pf[m], vf, o[m][dc8], 0, 0, 0);
            }
        }
    }

    // phased fp32 combine across the 4 waves (obuf aliases pbuf -- safe after barrier)
    float* obuf = (float*)smem;                 // 64 x 132
    float* lbuf = (float*)(smem + 33792);       // 64
    for (int ph = 0; ph < 4; ph++) {
        __syncthreads();
        if (w == ph) {
            if (ph == 0) {
#pragma unroll
                for (int m = 0; m < 4; m++) {
#pragma unroll
                    for (int dc8 = 0; dc8 < 8; dc8++)
#pragma unroll
                        for (int r = 0; r < 4; r++)
                            obuf[(m * 16 + quad * 4 + r) * 132 + dc8 * 16 + lc] = o[m][dc8][r];
#pragma unroll
                    for (int r = 0; r < 4; r++) lbuf[m * 16 + quad * 4 + r] = lacc[m][r];
                }
            } else {
#pragma unroll
                for (int m = 0; m < 4; m++) {
#pragma unroll
                    for (int dc8 = 0; dc8 < 8; dc8++)
#pragma unroll
                        for (int r = 0; r < 4; r++)
                            obuf[(m * 16 + quad * 4 + r) * 132 + dc8 * 16 + lc] += o[m][dc8][r];
#pragma unroll
                    for (int r = 0; r < 4; r++) lbuf[m * 16 + quad * 4 + r] += lacc[m][r];
                }
            }
        }
    }
    __syncthreads();

    // cooperative normalize + store: thread -> (row = tid/4, 32 cols)
    int row = tid >> 2;                 // 0..63: head m = row>>4, token off = row&15
    int m = row >> 4;
    int cb = (tid & 3) * 32;
    float inv = 1.0f / lbuf[row];
    int token = qbase + (row & 15);
    size_t base = ((size_t)(b * T_SEQ + token) * NQH + g * 4 + m) * HD + cb;
#pragma unroll
    for (int v4 = 0; v4 < 4; v4++) {
        union { u16 h[8]; uint4 u; } pk;
#pragma unroll
        for (int jj = 0; jj < 8; jj++)
            pk.h[jj] = f2b(obuf[row * 132 + cb + v4 * 8 + jj] * inv);
        *(uint4*)(ctx + base + v4 * 8) = pk.u;
    }
}

extern "C" void kernel_launch(void* const* d_in, const int* in_sizes, int n_in,
                              void* d_out, int out_size, void* d_ws, size_t ws_size,
                              hipStream_t stream) {
    const float* x  = (const float*)d_in[0];
    const float* Wq = (const float*)d_in[1];
    const float* Wk = (const float*)d_in[2];
    const float* Wv = (const float*)d_in[3];
    const float* Wo = (const float*)d_in[4];
    const float* ck = (const float*)d_in[5];
    const float* cv = (const float*)d_in[6];
    const int*   sp = (const int*)d_in[7];

    char* p = (char*)d_ws;
    u16* xb   = (u16*)p;                                  // x bf16 (dead after GEMM1)
    u16* qh   = xb;                                       //   aliased: q_h after GEMM1
    p += (size_t)TOKENS * EMBED * 2;                      // 16 MB
    u16* wqkv = (u16*)p; p += (size_t)QKVN * EMBED * 2;   // 48 MB
    u16* wob  = (u16*)p; p += (size_t)EMBED * EMBED * 2;  // 32 MB
    u16* qkvb = (u16*)p;                                  // 24 MB bf16 (dead after rope+vpack)
    u16* ctx  = qkvb;                                     //   aliased: ctx (16 MB) after vpack
    p += (size_t)TOKENS * QKVN * 2;
    u16* kh   = (u16*)p; p += (size_t)2 * NKVH * SMAX * HD * 2;  // 8 MB
    u16* vt8  = (u16*)p;                                         // 8 MB

    static int gemm_attr = 0;
    if (!gemm_attr) {
        hipFuncSetAttribute(reinterpret_cast<const void*>(&gemm256_kernel<true>),
                            hipFuncAttributeMaxDynamicSharedMemorySize, 131072);
        hipFuncSetAttribute(reinterpret_cast<const void*>(&gemm256_kernel<false>),
                            hipFuncAttributeMaxDynamicSharedMemorySize, 131072);
        gemm_attr = 1;
    }

    convert_all_kernel<<<(CSEG4 + 255) / 256, 256, 0, stream>>>(x, Wq, Wk, Wv, Wo, xb, wqkv, wob);
    gemm256_kernel<true><<<dim3(QKVN / 256, TOKENS / 256), 512, 131072, stream>>>(xb, wqkv, qkvb, QKVN, EMBED);
    cache_prefix_kernel<<<256, 256, 0, stream>>>(ck, cv, sp, kh, vt8);
    rope_qk_kernel<<<TOKENS * 2560 / 256, 256, 0, stream>>>(qkvb, sp, qh, kh);
    vpack_kernel<<<1024, 256, 0, stream>>>(qkvb, sp, vt8);
    attn_kernel<<<1024, 256, 36864, stream>>>(qh, kh, vt8, sp, ctx);
    gemm256_kernel<false><<<dim3(EMBED / 256, TOKENS / 256), 512, 131072, stream>>>(ctx, wob, d_out, EMBED, EMBED);
}

// Round 3
// 383.987 us; speedup vs baseline: 1.0525x; 1.0525x over previous
//
#include <hip/hip_runtime.h>
#include <stdint.h>

typedef unsigned short u16;
typedef __attribute__((ext_vector_type(8))) short short8x;   // 8 x bf16 (4 VGPRs)
typedef __attribute__((ext_vector_type(4))) float floatx4;   // MFMA C/D

#define TOKENS 2048   // B*T
#define EMBED  4096
#define QKVN   6144   // 4096 q + 1024 k + 1024 v
#define T_SEQ  1024
#define SMAX   2048   // cache length (2*KV_SEQ_LEN)
#define NQH    32
#define NKVH   8
#define HD     128

// RNE f32 -> bf16 (finite inputs only)
static __device__ __forceinline__ u16 f2b(float f) {
    union { float f; uint32_t u; } v; v.f = f;
    uint32_t r = v.u + 0x7fffu + ((v.u >> 16) & 1u);
    return (u16)(r >> 16);
}
static __device__ __forceinline__ float b2f(u16 h) {
    union { uint32_t u; float f; } v; v.u = ((uint32_t)h) << 16; return v.f;
}

static __device__ __forceinline__ void gload_lds16(const u16* g, u16* l) {
    __builtin_amdgcn_global_load_lds(
        (const __attribute__((address_space(1))) uint32_t*)g,
        (__attribute__((address_space(3))) uint32_t*)l, 16, 0, 0);
}

// ---------------- fused f32 -> bf16 conversion for all 5 inputs ----------------
#define CSEG0 2097152              // x        (2048*4096/4)
#define CSEG1 6291456              // +Wq      (4096*4096/4)
#define CSEG2 7340032              // +Wk      (1024*4096/4)
#define CSEG3 8388608              // +Wv      (1024*4096/4)
#define CSEG4 12582912             // +Wo      (4096*4096/4)
__global__ void convert_all_kernel(const float* __restrict__ x,  const float* __restrict__ Wq,
                                   const float* __restrict__ Wk, const float* __restrict__ Wv,
                                   const float* __restrict__ Wo,
                                   u16* __restrict__ xb, u16* __restrict__ wqkv,
                                   u16* __restrict__ wob) {
    int i = blockIdx.x * blockDim.x + threadIdx.x;   // float4 index
    if (i >= CSEG4) return;
    const float4* src; uint2* dst; int off;
    if (i < CSEG0)      { src = (const float4*)x;  dst = (uint2*)xb;   off = i; }
    else if (i < CSEG1) { src = (const float4*)Wq; dst = (uint2*)wqkv; off = i - CSEG0; }
    else if (i < CSEG2) { src = (const float4*)Wk; dst = (uint2*)wqkv + 4194304; off = i - CSEG1; }
    else if (i < CSEG3) { src = (const float4*)Wv; dst = (uint2*)wqkv + 5242880; off = i - CSEG2; }
    else                { src = (const float4*)Wo; dst = (uint2*)wob;  off = i - CSEG3; }
    float4 f = src[off];
    union { u16 h[4]; uint2 v; } o;
    o.h[0] = f2b(f.x); o.h[1] = f2b(f.y); o.h[2] = f2b(f.z); o.h[3] = f2b(f.w);
    dst[off] = o.v;
}

// ---------------- GEMM1: C[M,N] = A[M,K] * B[N,K]^T, 256x256 tile ----------------
// 8 waves (2M x 4N), per-wave 128x64 (two 64-row strips), BK=64, 8-phase / 2 K-tiles,
// counted vmcnt (proven ledger). Fragments held in registers across phases --
// P1 loads {A0,B0} (12 ds_read), P2 {B1} (4), P3 {A1} (8), P4 {} (0): 24/K-tile vs 48.
#define HB(BUF, MAT, H) (lds + (((BUF) * 4 + (MAT) * 2 + (H)) * 8192))
#define STAGE(BUF, MAT, H, KT) do { \
    const u16* _g0 = (MAT) ? gB[H][0] : gA[H][0]; \
    const u16* _g1 = (MAT) ? gB[H][1] : gA[H][1]; \
    gload_lds16(_g0 + (size_t)(KT) * 64, HB(BUF, MAT, H) + dOff0); \
    gload_lds16(_g1 + (size_t)(KT) * 64, HB(BUF, MAT, H) + dOff1); \
} while (0)
#define WAIT4 asm volatile("s_waitcnt vmcnt(4)" ::: "memory")
#define WAIT0 asm volatile("s_waitcnt vmcnt(0)" ::: "memory")
#define NOSTG ((void)0)
#define NOLD  ((void)0)
#define LDA(CBUF, AH) do { const u16* _p = HB(CBUF, 0, AH); \
    _Pragma("unroll") \
    for (int _mi = 0; _mi < 4; _mi++) { \
        af[_mi][0] = *(const short8x*)(_p + offA[_mi][0]); \
        af[_mi][1] = *(const short8x*)(_p + offA[_mi][1]); } } while (0)
#define LDB(CBUF, BH) do { const u16* _p = HB(CBUF, 1, BH); \
    _Pragma("unroll") \
    for (int _ni = 0; _ni < 2; _ni++) { \
        bf[BH][_ni][0] = *(const short8x*)(_p + offB[_ni][0]); \
        bf[BH][_ni][1] = *(const short8x*)(_p + offB[_ni][1]); } } while (0)
#define PHASE(CBUF, AH, BH, LOADS, STAGES, ENDW) do { \
    LOADS; \
    STAGES; \
    __builtin_amdgcn_s_barrier(); \
    asm volatile("s_waitcnt lgkmcnt(0)" ::: "memory"); \
    __builtin_amdgcn_sched_barrier(0); \
    __builtin_amdgcn_s_setprio(1); \
    _Pragma("unroll") \
    for (int _kk = 0; _kk < 2; _kk++) \
        _Pragma("unroll") \
        for (int _mi = 0; _mi < 4; _mi++) \
            _Pragma("unroll") \
            for (int _ni = 0; _ni < 2; _ni++) \
                acc[AH][BH][_mi][_ni] = __builtin_amdgcn_mfma_f32_16x16x32_bf16( \
                    af[_mi][_kk], bf[BH][_ni][_kk], acc[AH][BH][_mi][_ni], 0, 0, 0); \
    __builtin_amdgcn_s_setprio(0); \
    ENDW; \
    __builtin_amdgcn_s_barrier(); \
    __builtin_amdgcn_sched_barrier(0); \
} while (0)

__global__ __launch_bounds__(512, 2) void gemm256_kernel(
    const u16* __restrict__ A, const u16* __restrict__ Bw,
    u16* __restrict__ Cv, int N, int K) {
    extern __shared__ __align__(16) u16 lds[];   // 128 KiB dynamic
    const int tid = threadIdx.x;
    const int lane = tid & 63, w = tid >> 6;
    const int quad = lane >> 4, lc = lane & 15;
    const int wm = w >> 2, wn = w & 3;           // 2M x 4N wave grid
    const int Mbase = blockIdx.y * 256, Nbase = blockIdx.x * 256;

    // ---- staging addresses: linear LDS dest, swizzled global source ----
    const int r8 = lane >> 3;                    // row within 8-row wave stripe
    const int sl = (lane & 7) ^ r8;              // pre-swizzled 16B slot in row
    const int srow = w * 8 + r8;                 // 0..63 within a 64-row load stripe
    const u16* gA[2][2];                         // [half][load]
    const u16* gB[2][2];
#pragma unroll
    for (int H = 0; H < 2; H++)
#pragma unroll
        for (int L = 0; L < 2; L++) {
            gA[H][L] = A  + (size_t)(Mbase + H * 128 + L * 64 + srow) * K + sl * 8;
            gB[H][L] = Bw + (size_t)(Nbase + H * 128 + L * 64 + srow) * K + sl * 8;
        }
    const int dOff0 = w * 8 * 64;                // wave-uniform LDS dests (u16)
    const int dOff1 = (64 + w * 8) * 64;

    // ---- ds_read offsets (u16) within a 128x64 half-buffer, swizzled ----
    int offA[4][2], offB[2][2];
    const int xsw = lc & 7;
#pragma unroll
    for (int mi = 0; mi < 4; mi++)
#pragma unroll
        for (int kk = 0; kk < 2; kk++)
            offA[mi][kk] = (wm * 64 + mi * 16 + lc) * 64 + (((kk * 4 + quad) ^ xsw) * 8);
#pragma unroll
    for (int ni = 0; ni < 2; ni++)
#pragma unroll
        for (int kk = 0; kk < 2; kk++)
            offB[ni][kk] = (wn * 32 + ni * 16 + lc) * 64 + (((kk * 4 + quad) ^ xsw) * 8);

    floatx4 acc[2][2][4][2] = {};                // [AH][BH][mi][ni]
    short8x af[4][2];                            // current A-half fragments
    short8x bf[2][2][2];                         // [BH][ni][kk] -- both B halves live

    // prologue: all of tile 0, then A0(1),B1(1); wait leaves only those 4 in flight
    STAGE(0, 0, 0, 0);
    STAGE(0, 1, 0, 0);
    STAGE(0, 1, 1, 0);
    STAGE(0, 0, 1, 0);
    STAGE(1, 0, 0, 1);
    STAGE(1, 1, 1, 1);
    WAIT4;
    __builtin_amdgcn_s_barrier();
    __builtin_amdgcn_sched_barrier(0);

    const int NT = K >> 6;                       // 64 for K=4096 (even)
    for (int t = 0; t < NT - 2; t += 2) {
        // tile t (buf 0)
        PHASE(0, 0, 0, LDA(0, 0); LDB(0, 0), STAGE(1, 0, 1, t + 1); STAGE(1, 1, 0, t + 1), NOSTG);
        PHASE(0, 0, 1, LDB(0, 1), NOSTG, NOSTG);
        PHASE(0, 1, 1, LDA(0, 1), STAGE(0, 0, 0, t + 2), NOSTG);
        PHASE(0, 1, 0, NOLD, STAGE(0, 1, 1, t + 2), WAIT4);
        // tile t+1 (buf 1)
        PHASE(1, 0, 0, LDA(1, 0); LDB(1, 0), STAGE(0, 0, 1, t + 2); STAGE(0, 1, 0, t + 2), NOSTG);
        PHASE(1, 0, 1, LDB(1, 1), NOSTG, NOSTG);
        PHASE(1, 1, 1, LDA(1, 1), STAGE(1, 0, 0, t + 3), NOSTG);
        PHASE(1, 1, 0, NOLD, STAGE(1, 1, 1, t + 3), WAIT4);
    }
    // tile NT-2 (buf 0): finish staging tile NT-1, then drain fully
    PHASE(0, 0, 0, LDA(0, 0); LDB(0, 0), STAGE(1, 0, 1, NT - 1); STAGE(1, 1, 0, NT - 1), NOSTG);
    PHASE(0, 0, 1, LDB(0, 1), NOSTG, NOSTG);
    PHASE(0, 1, 1, LDA(0, 1), NOSTG, NOSTG);
    PHASE(0, 1, 0, NOLD, NOSTG, WAIT0);
    // tile NT-1 (buf 1)
    PHASE(1, 0, 0, LDA(1, 0); LDB(1, 0), NOSTG, NOSTG);
    PHASE(1, 0, 1, LDB(1, 1), NOSTG, NOSTG);
    PHASE(1, 1, 1, LDA(1, 1), NOSTG, NOSTG);
    PHASE(1, 1, 0, NOLD, NOSTG, NOSTG);

    // epilogue C write (C/D layout: col = lane&15, row = quad*4 + r)
#pragma unroll
    for (int AH = 0; AH < 2; AH++)
#pragma unroll
        for (int mi = 0; mi < 4; mi++) {
            const int row0 = Mbase + AH * 128 + wm * 64 + mi * 16 + quad * 4;
#pragma unroll
            for (int BH = 0; BH < 2; BH++)
#pragma unroll
                for (int ni = 0; ni < 2; ni++) {
                    const int col = Nbase + BH * 128 + wn * 32 + ni * 16 + lc;
#pragma unroll
                    for (int r = 0; r < 4; r++)
                        Cv[(size_t)(row0 + r) * N + col] = f2b(acc[AH][BH][mi][ni][r]);
                }
        }
}
#undef HB
#undef STAGE
#undef LDA
#undef LDB
#undef PHASE

// ---------------- GEMM2: C[M,N](f32) = A[M,K] * B[N,K]^T, 128x256 tile ----------------
// Full-machine grid for M=2048,N=4096 (16x16=256 blocks). 8 waves, per-wave 64x64
// (two 32-row strips x one 64-col strip). 2 phases / K-tile: P1 = A-half0 x all B
// (12 ds_read, 16 MFMA), P2 = A-half1 (4 ds_read, 16 MFMA). B fragments (8) held in
// registers the whole tile. Ledger: 6 loads/tile {A0,A1,B(4)}; issue A1(t+1)@P1,
// A0+B(t+2)@P2; boundary WAIT5 drains exactly through tile t+1's loads; 1.5 tiles in flight.
#define HA2(BUF, H) (lds + (BUF) * 24576 + (H) * 4096)
#define HBB2(BUF)   (lds + (BUF) * 24576 + 8192)
#define STGA2(BUF, H, KT) gload_lds16(gA2[H] + (size_t)(KT) * 64, HA2(BUF, H) + dOffW)
#define STGB2(BUF, KT) do { \
    _Pragma("unroll") \
    for (int _L = 0; _L < 4; _L++) \
        gload_lds16(gB2[_L] + (size_t)(KT) * 64, HBB2(BUF) + _L * 4096 + dOffW); \
} while (0)
#define WAIT5 asm volatile("s_waitcnt vmcnt(5)" ::: "memory")
#define LDA2(CBUF, AH) do { const u16* _p = HA2(CBUF, AH); \
    _Pragma("unroll") \
    for (int _mi = 0; _mi < 2; _mi++) { \
        af2[_mi][0] = *(const short8x*)(_p + offA2[_mi][0]); \
        af2[_mi][1] = *(const short8x*)(_p + offA2[_mi][1]); } } while (0)
#define LDB2(CBUF) do { const u16* _p = HBB2(CBUF); \
    _Pragma("unroll") \
    for (int _nj = 0; _nj < 4; _nj++) { \
        bf2[_nj][0] = *(const short8x*)(_p + offB2[_nj][0]); \
        bf2[_nj][1] = *(const short8x*)(_p + offB2[_nj][1]); } } while (0)
#define PHASE2(CBUF, AH, LOADS, STAGES, ENDW) do { \
    LOADS; \
    STAGES; \
    __builtin_amdgcn_s_barrier(); \
    asm volatile("s_waitcnt lgkmcnt(0)" ::: "memory"); \
    __builtin_amdgcn_sched_barrier(0); \
    __builtin_amdgcn_s_setprio(1); \
    _Pragma("unroll") \
    for (int _kk = 0; _kk < 2; _kk++) \
        _Pragma("unroll") \
        for (int _mi = 0; _mi < 2; _mi++) \
            _Pragma("unroll") \
            for (int _nj = 0; _nj < 4; _nj++) \
                acc2[AH][_mi][_nj] = __builtin_amdgcn_mfma_f32_16x16x32_bf16( \
                    af2[_mi][_kk], bf2[_nj][_kk], acc2[AH][_mi][_nj], 0, 0, 0); \
    __builtin_amdgcn_s_setprio(0); \
    ENDW; \
    __builtin_amdgcn_s_barrier(); \
    __builtin_amdgcn_sched_barrier(0); \
} while (0)

__global__ __launch_bounds__(512, 2) void gemmko_kernel(
    const u16* __restrict__ A, const u16* __restrict__ Bw,
    float* __restrict__ C, int N, int K) {
    extern __shared__ __align__(16) u16 lds[];   // 96 KiB dynamic
    const int tid = threadIdx.x;
    const int lane = tid & 63, w = tid >> 6;
    const int quad = lane >> 4, lc = lane & 15;
    const int wm = (w >> 2) & 1, wn = w & 3;     // 2M x 4N wave grid
    const int Mbase = blockIdx.y * 128, Nbase = blockIdx.x * 256;

    const int r8 = lane >> 3;
    const int sl = (lane & 7) ^ r8;              // pre-swizzled 16B slot
    const int srow = w * 8 + r8;                 // 0..63 within a 64-row unit
    const u16* gA2[2];
    const u16* gB2[4];
#pragma unroll
    for (int H = 0; H < 2; H++)
        gA2[H] = A + (size_t)(Mbase + H * 64 + srow) * K + sl * 8;
#pragma unroll
    for (int L = 0; L < 4; L++)
        gB2[L] = Bw + (size_t)(Nbase + L * 64 + srow) * K + sl * 8;
    const int dOffW = w * 512;                   // wave-uniform LDS dest (u16)

    int offA2[2][2], offB2[4][2];
    const int xsw = lc & 7;
#pragma unroll
    for (int mi = 0; mi < 2; mi++)
#pragma unroll
        for (int kk = 0; kk < 2; kk++)
            offA2[mi][kk] = (wm * 32 + mi * 16 + lc) * 64 + (((kk * 4 + quad) ^ xsw) * 8);
#pragma unroll
    for (int nj = 0; nj < 4; nj++)
#pragma unroll
        for (int kk = 0; kk < 2; kk++)
            offB2[nj][kk] = (wn * 64 + nj * 16 + lc) * 64 + (((kk * 4 + quad) ^ xsw) * 8);

    floatx4 acc2[2][2][4] = {};                  // [AH][mi][nj]
    short8x af2[2][2], bf2[4][2];

    // prologue: tile0 fully (6), tile1 A0+B (5); wait drains tile0's 6
    STGA2(0, 0, 0); STGA2(0, 1, 0); STGB2(0, 0);
    STGA2(1, 0, 1); STGB2(1, 1);
    WAIT5;
    __builtin_amdgcn_s_barrier();
    __builtin_amdgcn_sched_barrier(0);

    const int NT = K >> 6;                       // 64
    for (int t = 0; t < NT - 2; t += 2) {
        PHASE2(0, 0, LDA2(0, 0); LDB2(0), STGA2(1, 1, t + 1), NOSTG);
        PHASE2(0, 1, LDA2(0, 1), STGA2(0, 0, t + 2); STGB2(0, t + 2), WAIT5);
        PHASE2(1, 0, LDA2(1, 0); LDB2(1), STGA2(0, 1, t + 2), NOSTG);
        PHASE2(1, 1, LDA2(1, 1), STGA2(1, 0, t + 3); STGB2(1, t + 3), WAIT5);
    }
    PHASE2(0, 0, LDA2(0, 0); LDB2(0), STGA2(1, 1, NT - 1), NOSTG);
    PHASE2(0, 1, LDA2(0, 1), NOSTG, WAIT0);
    PHASE2(1, 0, LDA2(1, 0); LDB2(1), NOSTG, NOSTG);
    PHASE2(1, 1, LDA2(1, 1), NOSTG, NOSTG);

    // epilogue (f32 out)
#pragma unroll
    for (int AH = 0; AH < 2; AH++)
#pragma unroll
        for (int mi = 0; mi < 2; mi++) {
            const int row0 = Mbase + AH * 64 + wm * 32 + mi * 16 + quad * 4;
#pragma unroll
            for (int nj = 0; nj < 4; nj++) {
                const int col = Nbase + wn * 64 + nj * 16 + lc;
#pragma unroll
                for (int r = 0; r < 4; r++)
                    C[(size_t)(row0 + r) * N + col] = acc2[AH][mi][nj][r];
            }
        }
}
#undef HA2
#undef HBB2
#undef STGA2
#undef STGB2
#undef WAIT5
#undef LDA2
#undef LDB2
#undef PHASE2
#undef WAIT4
#undef WAIT0
#undef NOSTG
#undef NOLD

// ---------------- cache prefix copy (no-op when start_pos==0) ----------------
// kh: (b,g,s,d) row-major. vt8: 8-token interleaved (s>>3)*1024 + d*8 + (s&7).
__global__ void cache_prefix_kernel(const float* __restrict__ ck, const float* __restrict__ cv,
                                    const int* __restrict__ sp,
                                    u16* __restrict__ kh, u16* __restrict__ vt8) {
    int spos = sp[0];
    long total = (long)2 * spos * NKVH * HD;
    for (long i = (long)blockIdx.x * blockDim.x + threadIdx.x; i < total; i += (long)gridDim.x * blockDim.x) {
        long d = i % HD, rest = i / HD;
        long g = rest % NKVH; rest /= NKVH;
        long s = rest % spos; long b = rest / spos;
        float kv = ck[((b * SMAX + s) * NKVH + g) * HD + d];
        kh[((b * NKVH + g) * SMAX + s) * HD + d] = f2b(kv);
        float vv = cv[((b * SMAX + s) * NKVH + g) * HD + d];
        vt8[(size_t)(b * NKVH + g) * SMAX * HD + (s >> 3) * 1024 + d * 8 + (s & 7)] = f2b(vv);
    }
}

// ---------------- RoPE for Q and K (reads bf16 qkv) ----------------
__global__ void rope_qk_kernel(const u16* __restrict__ qkvb, const int* __restrict__ sp,
                               u16* __restrict__ qh, u16* __restrict__ kh) {
    int spos = sp[0];
    int idx = blockIdx.x * blockDim.x + threadIdx.x;   // tok*2560 + u
    int tok = idx / 2560;
    int u = idx - tok * 2560;
    int b = tok >> 10, t = tok & 1023;
    float pos = (float)(spos + t);
    const u16* src = qkvb + (size_t)tok * QKVN;
    const float kScale = 0.08838834764831845f;  // 1/sqrt(128)
    const float kLog = -0.20762050593045857f;   // -log2(10000)/64
    if (u < 2048) {                 // q: 32 heads x 64 pairs
        int h = u >> 6, i = u & 63;
        float ang = pos * exp2f((float)i * kLog);
        float cs = cosf(ang), sn = sinf(ang);
        float x0 = b2f(src[h * HD + 2 * i]), x1 = b2f(src[h * HD + 2 * i + 1]);
        size_t dst = (((size_t)(b * NQH + h) * T_SEQ) + t) * HD + 2 * i;
        qh[dst]     = f2b((x0 * cs - x1 * sn) * kScale);
        qh[dst + 1] = f2b((x0 * sn + x1 * cs) * kScale);
    } else {                        // k: 8 heads x 64 pairs
        int u2 = u - 2048;
        int g = u2 >> 6, i = u2 & 63;
        float ang = pos * exp2f((float)i * kLog);
        float cs = cosf(ang), sn = sinf(ang);
        float x0 = b2f(src[EMBED + g * HD + 2 * i]), x1 = b2f(src[EMBED + g * HD + 2 * i + 1]);
        size_t dst = (((size_t)(b * NKVH + g) * SMAX) + spos + t) * HD + 2 * i;
        kh[dst]     = f2b(x0 * cs - x1 * sn);
        kh[dst + 1] = f2b(x0 * sn + x1 * cs);
    }
}

// ---------------- V pack: bf16 qkv -> 8-token-interleaved vt8 (LDS transpose) ----------------
// Block: one (b, g, 16-token tile). Coalesced reads (256B rows) and writes (1KB waves).
__global__ __launch_bounds__(256) void vpack_kernel(const u16* __restrict__ qkvb,
                                                    const int* __restrict__ sp,
                                                    u16* __restrict__ vt8) {
    __shared__ u16 lds[16 * 136];
    int spos = sp[0];
    int tile = blockIdx.x;          // b*512 + g*64 + t16
    int t16 = tile & 63;
    int g = (tile >> 6) & 7;
    int b = tile >> 9;
    int tok0 = t16 * 16;
    int tid = threadIdx.x;
    {
        int srow = tid >> 4, dc8 = (tid & 15) * 8;
        const u16* src = qkvb + (size_t)(b * T_SEQ + tok0 + srow) * QKVN + 5120 + g * HD + dc8;
        *(uint4*)(lds + srow * 136 + dc8) = *(const uint4*)src;
    }
    __syncthreads();
    int d = tid & 127, half = tid >> 7;
    u16* vpg = vt8 + (size_t)(b * NKVH + g) * SMAX * HD;
    int s0 = spos + tok0;
    u16 val[8];
#pragma unroll
    for (int k = 0; k < 8; k++) val[k] = lds[(half * 8 + k) * 136 + d];
    if ((s0 & 7) == 0) {
        union { u16 h[8]; uint4 u; } pk;
#pragma unroll
        for (int k = 0; k < 8; k++) pk.h[k] = val[k];
        *(uint4*)(vpg + (size_t)((s0 >> 3) + half) * 1024 + d * 8) = pk.u;
    } else {
#pragma unroll
        for (int k = 0; k < 8; k++) {
            int s = s0 + half * 8 + k;
            vpg[(size_t)(s >> 3) * 1024 + d * 8 + (s & 7)] = val[k];
        }
    }
}

// ---------------- causal GQA flash attention v4 ----------------
// Wave M=64 rows = 4 Q-heads (one KV group) x 16 tokens. Block = 4 waves on one
// (b,g,16-token tile), 4-way round-robin key split, fp32 LDS combine. Fixed
// softmax max (m=0); row-sum via ones-B MFMA. V in 8-token-interleaved layout.
// Long causal tiles dispatch first (j reversed) to shrink the tail.
__global__ __launch_bounds__(256, 2) void attn_kernel(
    const u16* __restrict__ qh, const u16* __restrict__ kh,
    const u16* __restrict__ vt8, const int* __restrict__ sp,
    u16* __restrict__ ctx) {
    extern __shared__ __align__(16) char smem[];
    int spos = sp[0];
    int tid = threadIdx.x, w = tid >> 6, lane = tid & 63;
    int quad = lane >> 4, lc = lane & 15;
    int tile = blockIdx.x;          // b*512 + g*64 + (63-j)
    int j = 63 - (tile & 63);       // longest-first dispatch
    int g = (tile >> 6) & 7;
    int b = tile >> 9;
    int qbase = j * 16;

    const u16* kp = kh + (size_t)(b * NKVH + g) * SMAX * HD;
    const u16* vp = vt8 + (size_t)(b * NKVH + g) * SMAX * HD;

    short8x qf[4][4];
#pragma unroll
    for (int m = 0; m < 4; m++) {
        const u16* qp = qh + ((size_t)(b * NQH + g * 4 + m) * T_SEQ + qbase + lc) * HD + quad * 8;
#pragma unroll
        for (int dc = 0; dc < 4; dc++)
            qf[m][dc] = *(const short8x*)(qp + dc * 32);
    }
    short8x ones;
#pragma unroll
    for (int jj = 0; jj < 8; jj++) ones[jj] = (short)0x3F80;   // bf16 1.0

    floatx4 o[4][8] = {};
    floatx4 lacc[4] = {};
    int rowpos = spos + qbase + quad * 4;      // +r = absolute query position
    int nch = (spos + qbase + 16 + 63) >> 6;   // 64-key chunks
    u16* pw = (u16*)smem + w * 4608;           // this wave's P buffer (4 tiles x 16x72)

    for (int c = w; c < nch; c += 4) {
        int koff = c * 64;
#pragma unroll
        for (int st = 0; st < 4; st++) {
            const u16* kr = kp + (size_t)(koff + st * 16 + lc) * HD + quad * 8;
            floatx4 sc[4] = {};
#pragma unroll
            for (int dc = 0; dc < 4; dc++) {
                short8x kf = *(const short8x*)(kr + dc * 32);
#pragma unroll
                for (int m = 0; m < 4; m++)
                    sc[m] = __builtin_amdgcn_mfma_f32_16x16x32_bf16(qf[m][dc], kf, sc[m], 0, 0, 0);
            }
            int skey = koff + st * 16 + lc;
#pragma unroll
            for (int m = 0; m < 4; m++)
#pragma unroll
                for (int r = 0; r < 4; r++) {
                    float p = (skey <= rowpos + r) ? __expf(sc[m][r]) : 0.0f;
                    pw[m * 1152 + (quad * 4 + r) * 72 + st * 16 + lc] = f2b(p);
                }
        }
        asm volatile("s_waitcnt lgkmcnt(0)" ::: "memory");
#pragma unroll
        for (int hf = 0; hf < 2; hf++) {
            short8x pf[4];
#pragma unroll
            for (int m = 0; m < 4; m++)
                pf[m] = *(const short8x*)(pw + m * 1152 + lc * 72 + hf * 32 + quad * 8);
#pragma unroll
            for (int m = 0; m < 4; m++)
                lacc[m] = __builtin_amdgcn_mfma_f32_16x16x32_bf16(pf[m], ones, lacc[m], 0, 0, 0);
            const u16* vbase = vp + ((size_t)koff << 7) + (size_t)(hf * 4 + quad) * 1024 + lc * 8;
#pragma unroll
            for (int dc8 = 0; dc8 < 8; dc8++) {
                short8x vf = *(const short8x*)(vbase + dc8 * 128);
#pragma unroll
                for (int m = 0; m < 4; m++)
                    o[m][dc8] = __builtin_amdgcn_mfma_f32_16x16x32_bf16(pf[m], vf, o[m][dc8], 0, 0, 0);
            }
        }
    }

    // phased fp32 combine across the 4 waves (obuf aliases pbuf -- safe after barrier)
    float* obuf = (float*)smem;                 // 64 x 132
    float* lbuf = (float*)(smem + 33792);       // 64
    for (int ph = 0; ph < 4; ph++) {
        __syncthreads();
        if (w == ph) {
            if (ph == 0) {
#pragma unroll
                for (int m = 0; m < 4; m++) {
#pragma unroll
                    for (int dc8 = 0; dc8 < 8; dc8++)
#pragma unroll
                        for (int r = 0; r < 4; r++)
                            obuf[(m * 16 + quad * 4 + r) * 132 + dc8 * 16 + lc] = o[m][dc8][r];
#pragma unroll
                    for (int r = 0; r < 4; r++) lbuf[m * 16 + quad * 4 + r] = lacc[m][r];
                }
            } else {
#pragma unroll
                for (int m = 0; m < 4; m++) {
#pragma unroll
                    for (int dc8 = 0; dc8 < 8; dc8++)
#pragma unroll
                        for (int r = 0; r < 4; r++)
                            obuf[(m * 16 + quad * 4 + r) * 132 + dc8 * 16 + lc] += o[m][dc8][r];
#pragma unroll
                    for (int r = 0; r < 4; r++) lbuf[m * 16 + quad * 4 + r] += lacc[m][r];
                }
            }
        }
    }
    __syncthreads();

    // cooperative normalize + store: thread -> (row = tid/4, 32 cols)
    int row = tid >> 2;                 // 0..63: head m = row>>4, token off = row&15
    int m = row >> 4;
    int cb = (tid & 3) * 32;
    float inv = 1.0f / lbuf[row];
    int token = qbase + (row & 15);
    size_t base = ((size_t)(b * T_SEQ + token) * NQH + g * 4 + m) * HD + cb;
#pragma unroll
    for (int v4 = 0; v4 < 4; v4++) {
        union { u16 h[8]; uint4 u; } pk;
#pragma unroll
        for (int jj = 0; jj < 8; jj++)
            pk.h[jj] = f2b(obuf[row * 132 + cb + v4 * 8 + jj] * inv);
        *(uint4*)(ctx + base + v4 * 8) = pk.u;
    }
}

extern "C" void kernel_launch(void* const* d_in, const int* in_sizes, int n_in,
                              void* d_out, int out_size, void* d_ws, size_t ws_size,
                              hipStream_t stream) {
    const float* x  = (const float*)d_in[0];
    const float* Wq = (const float*)d_in[1];
    const float* Wk = (const float*)d_in[2];
    const float* Wv = (const float*)d_in[3];
    const float* Wo = (const float*)d_in[4];
    const float* ck = (const float*)d_in[5];
    const float* cv = (const float*)d_in[6];
    const int*   sp = (const int*)d_in[7];

    char* p = (char*)d_ws;
    u16* xb   = (u16*)p;                                  // x bf16 (dead after GEMM1)
    u16* qh   = xb;                                       //   aliased: q_h after GEMM1
    p += (size_t)TOKENS * EMBED * 2;                      // 16 MB
    u16* wqkv = (u16*)p; p += (size_t)QKVN * EMBED * 2;   // 48 MB
    u16* wob  = (u16*)p; p += (size_t)EMBED * EMBED * 2;  // 32 MB
    u16* qkvb = (u16*)p;                                  // 24 MB bf16 (dead after rope+vpack)
    u16* ctx  = qkvb;                                     //   aliased: ctx (16 MB) after vpack
    p += (size_t)TOKENS * QKVN * 2;
    u16* kh   = (u16*)p; p += (size_t)2 * NKVH * SMAX * HD * 2;  // 8 MB
    u16* vt8  = (u16*)p;                                         // 8 MB

    static int gemm_attr = 0;
    if (!gemm_attr) {
        (void)hipFuncSetAttribute(reinterpret_cast<const void*>(&gemm256_kernel),
                                  hipFuncAttributeMaxDynamicSharedMemorySize, 131072);
        (void)hipFuncSetAttribute(reinterpret_cast<const void*>(&gemmko_kernel),
                                  hipFuncAttributeMaxDynamicSharedMemorySize, 98304);
        gemm_attr = 1;
    }

    convert_all_kernel<<<(CSEG4 + 255) / 256, 256, 0, stream>>>(x, Wq, Wk, Wv, Wo, xb, wqkv, wob);
    gemm256_kernel<<<dim3(QKVN / 256, TOKENS / 256), 512, 131072, stream>>>(xb, wqkv, qkvb, QKVN, EMBED);
    cache_prefix_kernel<<<256, 256, 0, stream>>>(ck, cv, sp, kh, vt8);
    rope_qk_kernel<<<TOKENS * 2560 / 256, 256, 0, stream>>>(qkvb, sp, qh, kh);
    vpack_kernel<<<1024, 256, 0, stream>>>(qkvb, sp, vt8);
    attn_kernel<<<1024, 256, 36864, stream>>>(qh, kh, vt8, sp, ctx);
    gemmko_kernel<<<dim3(EMBED / 256, TOKENS / 128), 512, 98304, stream>>>(ctx, wob, (float*)d_out, EMBED, EMBED);
}

// Round 4
// 382.963 us; speedup vs baseline: 1.0553x; 1.0027x over previous
//
#include <hip/hip_runtime.h>
#include <stdint.h>

typedef unsigned short u16;
typedef __attribute__((ext_vector_type(8))) short short8x;   // 8 x bf16 (4 VGPRs)
typedef __attribute__((ext_vector_type(4))) float floatx4;   // MFMA C/D

#define TOKENS 2048   // B*T
#define EMBED  4096
#define QKVN   6144   // 4096 q + 1024 k + 1024 v
#define T_SEQ  1024
#define SMAX   2048   // cache length (2*KV_SEQ_LEN)
#define NQH    32
#define NKVH   8
#define HD     128

// RNE f32 -> bf16 (finite inputs only)
static __device__ __forceinline__ u16 f2b(float f) {
    union { float f; uint32_t u; } v; v.f = f;
    uint32_t r = v.u + 0x7fffu + ((v.u >> 16) & 1u);
    return (u16)(r >> 16);
}
static __device__ __forceinline__ float b2f(u16 h) {
    union { uint32_t u; float f; } v; v.u = ((uint32_t)h) << 16; return v.f;
}

static __device__ __forceinline__ void gload_lds16(const u16* g, u16* l) {
    __builtin_amdgcn_global_load_lds(
        (const __attribute__((address_space(1))) uint32_t*)g,
        (__attribute__((address_space(3))) uint32_t*)l, 16, 0, 0);
}

// ---------------- fused f32 -> bf16 conversion for all 5 inputs ----------------
#define CSEG0 2097152              // x        (2048*4096/4)
#define CSEG1 6291456              // +Wq      (4096*4096/4)
#define CSEG2 7340032              // +Wk      (1024*4096/4)
#define CSEG3 8388608              // +Wv      (1024*4096/4)
#define CSEG4 12582912             // +Wo      (4096*4096/4)
__global__ void convert_all_kernel(const float* __restrict__ x,  const float* __restrict__ Wq,
                                   const float* __restrict__ Wk, const float* __restrict__ Wv,
                                   const float* __restrict__ Wo,
                                   u16* __restrict__ xb, u16* __restrict__ wqkv,
                                   u16* __restrict__ wob) {
    int i = blockIdx.x * blockDim.x + threadIdx.x;   // float4 index
    if (i >= CSEG4) return;
    const float4* src; uint2* dst; int off;
    if (i < CSEG0)      { src = (const float4*)x;  dst = (uint2*)xb;   off = i; }
    else if (i < CSEG1) { src = (const float4*)Wq; dst = (uint2*)wqkv; off = i - CSEG0; }
    else if (i < CSEG2) { src = (const float4*)Wk; dst = (uint2*)wqkv + 4194304; off = i - CSEG1; }
    else if (i < CSEG3) { src = (const float4*)Wv; dst = (uint2*)wqkv + 5242880; off = i - CSEG2; }
    else                { src = (const float4*)Wo; dst = (uint2*)wob;  off = i - CSEG3; }
    float4 f = src[off];
    union { u16 h[4]; uint2 v; } o;
    o.h[0] = f2b(f.x); o.h[1] = f2b(f.y); o.h[2] = f2b(f.z); o.h[3] = f2b(f.w);
    dst[off] = o.v;
}

// ---------------- GEMM1: C[M,N] = A[M,K] * B[N,K]^T, 256x256 tile ----------------
// 8 waves (2M x 4N), per-wave 128x64 (two 64-row strips), BK=64, 8-phase / 2 K-tiles,
// counted vmcnt (proven ledger). Fragments held in registers across phases --
// P1 loads {A0,B0} (12 ds_read), P2 {B1} (4), P3 {A1} (8), P4 {} (0): 24/K-tile vs 48.
// launch_bounds(512,1): LDS (128KiB) already forces 1 block/CU; the previous ",2"
// capped VGPRs at 128 and spilled the fragment arrays to scratch (R3 regression).
#define HB(BUF, MAT, H) (lds + (((BUF) * 4 + (MAT) * 2 + (H)) * 8192))
#define STAGE(BUF, MAT, H, KT) do { \
    const u16* _g0 = (MAT) ? gB[H][0] : gA[H][0]; \
    const u16* _g1 = (MAT) ? gB[H][1] : gA[H][1]; \
    gload_lds16(_g0 + (size_t)(KT) * 64, HB(BUF, MAT, H) + dOff0); \
    gload_lds16(_g1 + (size_t)(KT) * 64, HB(BUF, MAT, H) + dOff1); \
} while (0)
#define WAIT4 asm volatile("s_waitcnt vmcnt(4)" ::: "memory")
#define WAIT0 asm volatile("s_waitcnt vmcnt(0)" ::: "memory")
#define NOSTG ((void)0)
#define NOLD  ((void)0)
#define LDA(CBUF, AH) do { const u16* _p = HB(CBUF, 0, AH); \
    _Pragma("unroll") \
    for (int _mi = 0; _mi < 4; _mi++) { \
        af[_mi][0] = *(const short8x*)(_p + offA[_mi][0]); \
        af[_mi][1] = *(const short8x*)(_p + offA[_mi][1]); } } while (0)
#define LDB(CBUF, BH) do { const u16* _p = HB(CBUF, 1, BH); \
    _Pragma("unroll") \
    for (int _ni = 0; _ni < 2; _ni++) { \
        bf[BH][_ni][0] = *(const short8x*)(_p + offB[_ni][0]); \
        bf[BH][_ni][1] = *(const short8x*)(_p + offB[_ni][1]); } } while (0)
#define PHASE(CBUF, AH, BH, LOADS, STAGES, ENDW) do { \
    LOADS; \
    STAGES; \
    __builtin_amdgcn_s_barrier(); \
    asm volatile("s_waitcnt lgkmcnt(0)" ::: "memory"); \
    __builtin_amdgcn_sched_barrier(0); \
    __builtin_amdgcn_s_setprio(1); \
    _Pragma("unroll") \
    for (int _kk = 0; _kk < 2; _kk++) \
        _Pragma("unroll") \
        for (int _mi = 0; _mi < 4; _mi++) \
            _Pragma("unroll") \
            for (int _ni = 0; _ni < 2; _ni++) \
                acc[AH][BH][_mi][_ni] = __builtin_amdgcn_mfma_f32_16x16x32_bf16( \
                    af[_mi][_kk], bf[BH][_ni][_kk], acc[AH][BH][_mi][_ni], 0, 0, 0); \
    __builtin_amdgcn_s_setprio(0); \
    ENDW; \
    __builtin_amdgcn_s_barrier(); \
    __builtin_amdgcn_sched_barrier(0); \
} while (0)

__global__ __launch_bounds__(512, 1) void gemm256_kernel(
    const u16* __restrict__ A, const u16* __restrict__ Bw,
    u16* __restrict__ Cv, int N, int K) {
    extern __shared__ __align__(16) u16 lds[];   // 128 KiB dynamic
    const int tid = threadIdx.x;
    const int lane = tid & 63, w = tid >> 6;
    const int quad = lane >> 4, lc = lane & 15;
    const int wm = w >> 2, wn = w & 3;           // 2M x 4N wave grid
    const int Mbase = blockIdx.y * 256, Nbase = blockIdx.x * 256;

    // ---- staging addresses: linear LDS dest, swizzled global source ----
    const int r8 = lane >> 3;                    // row within 8-row wave stripe
    const int sl = (lane & 7) ^ r8;              // pre-swizzled 16B slot in row
    const int srow = w * 8 + r8;                 // 0..63 within a 64-row load stripe
    const u16* gA[2][2];                         // [half][load]
    const u16* gB[2][2];
#pragma unroll
    for (int H = 0; H < 2; H++)
#pragma unroll
        for (int L = 0; L < 2; L++) {
            gA[H][L] = A  + (size_t)(Mbase + H * 128 + L * 64 + srow) * K + sl * 8;
            gB[H][L] = Bw + (size_t)(Nbase + H * 128 + L * 64 + srow) * K + sl * 8;
        }
    const int dOff0 = w * 8 * 64;                // wave-uniform LDS dests (u16)
    const int dOff1 = (64 + w * 8) * 64;

    // ---- ds_read offsets (u16) within a 128x64 half-buffer, swizzled ----
    int offA[4][2], offB[2][2];
    const int xsw = lc & 7;
#pragma unroll
    for (int mi = 0; mi < 4; mi++)
#pragma unroll
        for (int kk = 0; kk < 2; kk++)
            offA[mi][kk] = (wm * 64 + mi * 16 + lc) * 64 + (((kk * 4 + quad) ^ xsw) * 8);
#pragma unroll
    for (int ni = 0; ni < 2; ni++)
#pragma unroll
        for (int kk = 0; kk < 2; kk++)
            offB[ni][kk] = (wn * 32 + ni * 16 + lc) * 64 + (((kk * 4 + quad) ^ xsw) * 8);

    floatx4 acc[2][2][4][2] = {};                // [AH][BH][mi][ni]
    short8x af[4][2];                            // current A-half fragments
    short8x bf[2][2][2];                         // [BH][ni][kk] -- both B halves live

    // prologue: all of tile 0, then A0(1),B1(1); wait leaves only those 4 in flight
    STAGE(0, 0, 0, 0);
    STAGE(0, 1, 0, 0);
    STAGE(0, 1, 1, 0);
    STAGE(0, 0, 1, 0);
    STAGE(1, 0, 0, 1);
    STAGE(1, 1, 1, 1);
    WAIT4;
    __builtin_amdgcn_s_barrier();
    __builtin_amdgcn_sched_barrier(0);

    const int NT = K >> 6;                       // 64 for K=4096 (even)
    for (int t = 0; t < NT - 2; t += 2) {
        // tile t (buf 0)
        PHASE(0, 0, 0, LDA(0, 0); LDB(0, 0), STAGE(1, 0, 1, t + 1); STAGE(1, 1, 0, t + 1), NOSTG);
        PHASE(0, 0, 1, LDB(0, 1), NOSTG, NOSTG);
        PHASE(0, 1, 1, LDA(0, 1), STAGE(0, 0, 0, t + 2), NOSTG);
        PHASE(0, 1, 0, NOLD, STAGE(0, 1, 1, t + 2), WAIT4);
        // tile t+1 (buf 1)
        PHASE(1, 0, 0, LDA(1, 0); LDB(1, 0), STAGE(0, 0, 1, t + 2); STAGE(0, 1, 0, t + 2), NOSTG);
        PHASE(1, 0, 1, LDB(1, 1), NOSTG, NOSTG);
        PHASE(1, 1, 1, LDA(1, 1), STAGE(1, 0, 0, t + 3), NOSTG);
        PHASE(1, 1, 0, NOLD, STAGE(1, 1, 1, t + 3), WAIT4);
    }
    // tile NT-2 (buf 0): finish staging tile NT-1, then drain fully
    PHASE(0, 0, 0, LDA(0, 0); LDB(0, 0), STAGE(1, 0, 1, NT - 1); STAGE(1, 1, 0, NT - 1), NOSTG);
    PHASE(0, 0, 1, LDB(0, 1), NOSTG, NOSTG);
    PHASE(0, 1, 1, LDA(0, 1), NOSTG, NOSTG);
    PHASE(0, 1, 0, NOLD, NOSTG, WAIT0);
    // tile NT-1 (buf 1)
    PHASE(1, 0, 0, LDA(1, 0); LDB(1, 0), NOSTG, NOSTG);
    PHASE(1, 0, 1, LDB(1, 1), NOSTG, NOSTG);
    PHASE(1, 1, 1, LDA(1, 1), NOSTG, NOSTG);
    PHASE(1, 1, 0, NOLD, NOSTG, NOSTG);

    // epilogue C write (C/D layout: col = lane&15, row = quad*4 + r)
#pragma unroll
    for (int AH = 0; AH < 2; AH++)
#pragma unroll
        for (int mi = 0; mi < 4; mi++) {
            const int row0 = Mbase + AH * 128 + wm * 64 + mi * 16 + quad * 4;
#pragma unroll
            for (int BH = 0; BH < 2; BH++)
#pragma unroll
                for (int ni = 0; ni < 2; ni++) {
                    const int col = Nbase + BH * 128 + wn * 32 + ni * 16 + lc;
#pragma unroll
                    for (int r = 0; r < 4; r++)
                        Cv[(size_t)(row0 + r) * N + col] = f2b(acc[AH][BH][mi][ni][r]);
                }
        }
}
#undef HB
#undef STAGE
#undef LDA
#undef LDB
#undef PHASE

// ---------------- GEMM2: C[M,N](f32) = A[M,K] * B[N,K]^T, 128x256 tile ----------------
// Full-machine grid for M=2048,N=4096 (16x16=256 blocks). 8 waves, per-wave 64x64
// (two 32-row strips x one 64-col strip). 2 phases / K-tile: P1 = A-half0 x all B
// (12 ds_read, 16 MFMA), P2 = A-half1 (4 ds_read, 16 MFMA). B fragments (8) held in
// registers the whole tile. Ledger: 6 loads/tile {A0,A1,B(4)}; issue A1(t+1)@P1,
// A0+B(t+2)@P2; boundary WAIT5 drains exactly through tile t+1's loads; 1.5 tiles in flight.
// launch_bounds(512,1): 96 KiB LDS already forces 1 block/CU; avoid the 128-VGPR cap.
#define HA2(BUF, H) (lds + (BUF) * 24576 + (H) * 4096)
#define HBB2(BUF)   (lds + (BUF) * 24576 + 8192)
#define STGA2(BUF, H, KT) gload_lds16(gA2[H] + (size_t)(KT) * 64, HA2(BUF, H) + dOffW)
#define STGB2(BUF, KT) do { \
    _Pragma("unroll") \
    for (int _L = 0; _L < 4; _L++) \
        gload_lds16(gB2[_L] + (size_t)(KT) * 64, HBB2(BUF) + _L * 4096 + dOffW); \
} while (0)
#define WAIT5 asm volatile("s_waitcnt vmcnt(5)" ::: "memory")
#define LDA2(CBUF, AH) do { const u16* _p = HA2(CBUF, AH); \
    _Pragma("unroll") \
    for (int _mi = 0; _mi < 2; _mi++) { \
        af2[_mi][0] = *(const short8x*)(_p + offA2[_mi][0]); \
        af2[_mi][1] = *(const short8x*)(_p + offA2[_mi][1]); } } while (0)
#define LDB2(CBUF) do { const u16* _p = HBB2(CBUF); \
    _Pragma("unroll") \
    for (int _nj = 0; _nj < 4; _nj++) { \
        bf2[_nj][0] = *(const short8x*)(_p + offB2[_nj][0]); \
        bf2[_nj][1] = *(const short8x*)(_p + offB2[_nj][1]); } } while (0)
#define PHASE2(CBUF, AH, LOADS, STAGES, ENDW) do { \
    LOADS; \
    STAGES; \
    __builtin_amdgcn_s_barrier(); \
    asm volatile("s_waitcnt lgkmcnt(0)" ::: "memory"); \
    __builtin_amdgcn_sched_barrier(0); \
    __builtin_amdgcn_s_setprio(1); \
    _Pragma("unroll") \
    for (int _kk = 0; _kk < 2; _kk++) \
        _Pragma("unroll") \
        for (int _mi = 0; _mi < 2; _mi++) \
            _Pragma("unroll") \
            for (int _nj = 0; _nj < 4; _nj++) \
                acc2[AH][_mi][_nj] = __builtin_amdgcn_mfma_f32_16x16x32_bf16( \
                    af2[_mi][_kk], bf2[_nj][_kk], acc2[AH][_mi][_nj], 0, 0, 0); \
    __builtin_amdgcn_s_setprio(0); \
    ENDW; \
    __builtin_amdgcn_s_barrier(); \
    __builtin_amdgcn_sched_barrier(0); \
} while (0)

__global__ __launch_bounds__(512, 1) void gemmko_kernel(
    const u16* __restrict__ A, const u16* __restrict__ Bw,
    float* __restrict__ C, int N, int K) {
    extern __shared__ __align__(16) u16 lds[];   // 96 KiB dynamic
    const int tid = threadIdx.x;
    const int lane = tid & 63, w = tid >> 6;
    const int quad = lane >> 4, lc = lane & 15;
    const int wm = (w >> 2) & 1, wn = w & 3;     // 2M x 4N wave grid
    const int Mbase = blockIdx.y * 128, Nbase = blockIdx.x * 256;

    const int r8 = lane >> 3;
    const int sl = (lane & 7) ^ r8;              // pre-swizzled 16B slot
    const int srow = w * 8 + r8;                 // 0..63 within a 64-row unit
    const u16* gA2[2];
    const u16* gB2[4];
#pragma unroll
    for (int H = 0; H < 2; H++)
        gA2[H] = A + (size_t)(Mbase + H * 64 + srow) * K + sl * 8;
#pragma unroll
    for (int L = 0; L < 4; L++)
        gB2[L] = Bw + (size_t)(Nbase + L * 64 + srow) * K + sl * 8;
    const int dOffW = w * 512;                   // wave-uniform LDS dest (u16)

    int offA2[2][2], offB2[4][2];
    const int xsw = lc & 7;
#pragma unroll
    for (int mi = 0; mi < 2; mi++)
#pragma unroll
        for (int kk = 0; kk < 2; kk++)
            offA2[mi][kk] = (wm * 32 + mi * 16 + lc) * 64 + (((kk * 4 + quad) ^ xsw) * 8);
#pragma unroll
    for (int nj = 0; nj < 4; nj++)
#pragma unroll
        for (int kk = 0; kk < 2; kk++)
            offB2[nj][kk] = (wn * 64 + nj * 16 + lc) * 64 + (((kk * 4 + quad) ^ xsw) * 8);

    floatx4 acc2[2][2][4] = {};                  // [AH][mi][nj]
    short8x af2[2][2], bf2[4][2];

    // prologue: tile0 fully (6), tile1 A0+B (5); wait drains tile0's 6
    STGA2(0, 0, 0); STGA2(0, 1, 0); STGB2(0, 0);
    STGA2(1, 0, 1); STGB2(1, 1);
    WAIT5;
    __builtin_amdgcn_s_barrier();
    __builtin_amdgcn_sched_barrier(0);

    const int NT = K >> 6;                       // 64
    for (int t = 0; t < NT - 2; t += 2) {
        PHASE2(0, 0, LDA2(0, 0); LDB2(0), STGA2(1, 1, t + 1), NOSTG);
        PHASE2(0, 1, LDA2(0, 1), STGA2(0, 0, t + 2); STGB2(0, t + 2), WAIT5);
        PHASE2(1, 0, LDA2(1, 0); LDB2(1), STGA2(0, 1, t + 2), NOSTG);
        PHASE2(1, 1, LDA2(1, 1), STGA2(1, 0, t + 3); STGB2(1, t + 3), WAIT5);
    }
    PHASE2(0, 0, LDA2(0, 0); LDB2(0), STGA2(1, 1, NT - 1), NOSTG);
    PHASE2(0, 1, LDA2(0, 1), NOSTG, WAIT0);
    PHASE2(1, 0, LDA2(1, 0); LDB2(1), NOSTG, NOSTG);
    PHASE2(1, 1, LDA2(1, 1), NOSTG, NOSTG);

    // epilogue (f32 out)
#pragma unroll
    for (int AH = 0; AH < 2; AH++)
#pragma unroll
        for (int mi = 0; mi < 2; mi++) {
            const int row0 = Mbase + AH * 64 + wm * 32 + mi * 16 + quad * 4;
#pragma unroll
            for (int nj = 0; nj < 4; nj++) {
                const int col = Nbase + wn * 64 + nj * 16 + lc;
#pragma unroll
                for (int r = 0; r < 4; r++)
                    C[(size_t)(row0 + r) * N + col] = acc2[AH][mi][nj][r];
            }
        }
}
#undef HA2
#undef HBB2
#undef STGA2
#undef STGB2
#undef WAIT5
#undef LDA2
#undef LDB2
#undef PHASE2
#undef WAIT4
#undef WAIT0
#undef NOSTG
#undef NOLD

// ---------------- cache prefix copy (no-op when start_pos==0) ----------------
// kh: (b,g,s,d) row-major. vt8: 8-token interleaved (s>>3)*1024 + d*8 + (s&7).
__global__ void cache_prefix_kernel(const float* __restrict__ ck, const float* __restrict__ cv,
                                    const int* __restrict__ sp,
                                    u16* __restrict__ kh, u16* __restrict__ vt8) {
    int spos = sp[0];
    long total = (long)2 * spos * NKVH * HD;
    for (long i = (long)blockIdx.x * blockDim.x + threadIdx.x; i < total; i += (long)gridDim.x * blockDim.x) {
        long d = i % HD, rest = i / HD;
        long g = rest % NKVH; rest /= NKVH;
        long s = rest % spos; long b = rest / spos;
        float kv = ck[((b * SMAX + s) * NKVH + g) * HD + d];
        kh[((b * NKVH + g) * SMAX + s) * HD + d] = f2b(kv);
        float vv = cv[((b * SMAX + s) * NKVH + g) * HD + d];
        vt8[(size_t)(b * NKVH + g) * SMAX * HD + (s >> 3) * 1024 + d * 8 + (s & 7)] = f2b(vv);
    }
}

// ---------------- RoPE for Q and K (reads bf16 qkv) ----------------
__global__ void rope_qk_kernel(const u16* __restrict__ qkvb, const int* __restrict__ sp,
                               u16* __restrict__ qh, u16* __restrict__ kh) {
    int spos = sp[0];
    int idx = blockIdx.x * blockDim.x + threadIdx.x;   // tok*2560 + u
    int tok = idx / 2560;
    int u = idx - tok * 2560;
    int b = tok >> 10, t = tok & 1023;
    float pos = (float)(spos + t);
    const u16* src = qkvb + (size_t)tok * QKVN;
    const float kScale = 0.08838834764831845f;  // 1/sqrt(128)
    const float kLog = -0.20762050593045857f;   // -log2(10000)/64
    if (u < 2048) {                 // q: 32 heads x 64 pairs
        int h = u >> 6, i = u & 63;
        float ang = pos * exp2f((float)i * kLog);
        float cs = cosf(ang), sn = sinf(ang);
        float x0 = b2f(src[h * HD + 2 * i]), x1 = b2f(src[h * HD + 2 * i + 1]);
        size_t dst = (((size_t)(b * NQH + h) * T_SEQ) + t) * HD + 2 * i;
        qh[dst]     = f2b((x0 * cs - x1 * sn) * kScale);
        qh[dst + 1] = f2b((x0 * sn + x1 * cs) * kScale);
    } else {                        // k: 8 heads x 64 pairs
        int u2 = u - 2048;
        int g = u2 >> 6, i = u2 & 63;
        float ang = pos * exp2f((float)i * kLog);
        float cs = cosf(ang), sn = sinf(ang);
        float x0 = b2f(src[EMBED + g * HD + 2 * i]), x1 = b2f(src[EMBED + g * HD + 2 * i + 1]);
        size_t dst = (((size_t)(b * NKVH + g) * SMAX) + spos + t) * HD + 2 * i;
        kh[dst]     = f2b(x0 * cs - x1 * sn);
        kh[dst + 1] = f2b(x0 * sn + x1 * cs);
    }
}

// ---------------- V pack: bf16 qkv -> 8-token-interleaved vt8 (LDS transpose) ----------------
// Block: one (b, g, 16-token tile). Coalesced reads (256B rows) and writes (1KB waves).
__global__ __launch_bounds__(256) void vpack_kernel(const u16* __restrict__ qkvb,
                                                    const int* __restrict__ sp,
                                                    u16* __restrict__ vt8) {
    __shared__ u16 lds[16 * 136];
    int spos = sp[0];
    int tile = blockIdx.x;          // b*512 + g*64 + t16
    int t16 = tile & 63;
    int g = (tile >> 6) & 7;
    int b = tile >> 9;
    int tok0 = t16 * 16;
    int tid = threadIdx.x;
    {
        int srow = tid >> 4, dc8 = (tid & 15) * 8;
        const u16* src = qkvb + (size_t)(b * T_SEQ + tok0 + srow) * QKVN + 5120 + g * HD + dc8;
        *(uint4*)(lds + srow * 136 + dc8) = *(const uint4*)src;
    }
    __syncthreads();
    int d = tid & 127, half = tid >> 7;
    u16* vpg = vt8 + (size_t)(b * NKVH + g) * SMAX * HD;
    int s0 = spos + tok0;
    u16 val[8];
#pragma unroll
    for (int k = 0; k < 8; k++) val[k] = lds[(half * 8 + k) * 136 + d];
    if ((s0 & 7) == 0) {
        union { u16 h[8]; uint4 u; } pk;
#pragma unroll
        for (int k = 0; k < 8; k++) pk.h[k] = val[k];
        *(uint4*)(vpg + (size_t)((s0 >> 3) + half) * 1024 + d * 8) = pk.u;
    } else {
#pragma unroll
        for (int k = 0; k < 8; k++) {
            int s = s0 + half * 8 + k;
            vpg[(size_t)(s >> 3) * 1024 + d * 8 + (s & 7)] = val[k];
        }
    }
}

// ---------------- causal GQA flash attention v4 ----------------
// Wave M=64 rows = 4 Q-heads (one KV group) x 16 tokens. Block = 4 waves on one
// (b,g,16-token tile), 4-way round-robin key split, fp32 LDS combine. Fixed
// softmax max (m=0); row-sum via ones-B MFMA. V in 8-token-interleaved layout.
// Long causal tiles dispatch first (j reversed) to shrink the tail.
__global__ __launch_bounds__(256, 2) void attn_kernel(
    const u16* __restrict__ qh, const u16* __restrict__ kh,
    const u16* __restrict__ vt8, const int* __restrict__ sp,
    u16* __restrict__ ctx) {
    extern __shared__ __align__(16) char smem[];
    int spos = sp[0];
    int tid = threadIdx.x, w = tid >> 6, lane = tid & 63;
    int quad = lane >> 4, lc = lane & 15;
    int tile = blockIdx.x;          // b*512 + g*64 + (63-j)
    int j = 63 - (tile & 63);       // longest-first dispatch
    int g = (tile >> 6) & 7;
    int b = tile >> 9;
    int qbase = j * 16;

    const u16* kp = kh + (size_t)(b * NKVH + g) * SMAX * HD;
    const u16* vp = vt8 + (size_t)(b * NKVH + g) * SMAX * HD;

    short8x qf[4][4];
#pragma unroll
    for (int m = 0; m < 4; m++) {
        const u16* qp = qh + ((size_t)(b * NQH + g * 4 + m) * T_SEQ + qbase + lc) * HD + quad * 8;
#pragma unroll
        for (int dc = 0; dc < 4; dc++)
            qf[m][dc] = *(const short8x*)(qp + dc * 32);
    }
    short8x ones;
#pragma unroll
    for (int jj = 0; jj < 8; jj++) ones[jj] = (short)0x3F80;   // bf16 1.0

    floatx4 o[4][8] = {};
    floatx4 lacc[4] = {};
    int rowpos = spos + qbase + quad * 4;      // +r = absolute query position
    int nch = (spos + qbase + 16 + 63) >> 6;   // 64-key chunks
    u16* pw = (u16*)smem + w * 4608;           // this wave's P buffer (4 tiles x 16x72)

    for (int c = w; c < nch; c += 4) {
        int koff = c * 64;
#pragma unroll
        for (int st = 0; st < 4; st++) {
            const u16* kr = kp + (size_t)(koff + st * 16 + lc) * HD + quad * 8;
            floatx4 sc[4] = {};
#pragma unroll
            for (int dc = 0; dc < 4; dc++) {
                short8x kf = *(const short8x*)(kr + dc * 32);
#pragma unroll
                for (int m = 0; m < 4; m++)
                    sc[m] = __builtin_amdgcn_mfma_f32_16x16x32_bf16(qf[m][dc], kf, sc[m], 0, 0, 0);
            }
            int skey = koff + st * 16 + lc;
#pragma unroll
            for (int m = 0; m < 4; m++)
#pragma unroll
                for (int r = 0; r < 4; r++) {
                    float p = (skey <= rowpos + r) ? __expf(sc[m][r]) : 0.0f;
                    pw[m * 1152 + (quad * 4 + r) * 72 + st * 16 + lc] = f2b(p);
                }
        }
        asm volatile("s_waitcnt lgkmcnt(0)" ::: "memory");
#pragma unroll
        for (int hf = 0; hf < 2; hf++) {
            short8x pf[4];
#pragma unroll
            for (int m = 0; m < 4; m++)
                pf[m] = *(const short8x*)(pw + m * 1152 + lc * 72 + hf * 32 + quad * 8);
#pragma unroll
            for (int m = 0; m < 4; m++)
                lacc[m] = __builtin_amdgcn_mfma_f32_16x16x32_bf16(pf[m], ones, lacc[m], 0, 0, 0);
            const u16* vbase = vp + ((size_t)koff << 7) + (size_t)(hf * 4 + quad) * 1024 + lc * 8;
#pragma unroll
            for (int dc8 = 0; dc8 < 8; dc8++) {
                short8x vf = *(const short8x*)(vbase + dc8 * 128);
#pragma unroll
                for (int m = 0; m < 4; m++)
                    o[m][dc8] = __builtin_amdgcn_mfma_f32_16x16x32_bf16(pf[m], vf, o[m][dc8], 0, 0, 0);
            }
        }
    }

    // phased fp32 combine across the 4 waves (obuf aliases pbuf -- safe after barrier)
    float* obuf = (float*)smem;                 // 64 x 132
    float* lbuf = (float*)(smem + 33792);       // 64
    for (int ph = 0; ph < 4; ph++) {
        __syncthreads();
        if (w == ph) {
            if (ph == 0) {
#pragma unroll
                for (int m = 0; m < 4; m++) {
#pragma unroll
                    for (int dc8 = 0; dc8 < 8; dc8++)
#pragma unroll
                        for (int r = 0; r < 4; r++)
                            obuf[(m * 16 + quad * 4 + r) * 132 + dc8 * 16 + lc] = o[m][dc8][r];
#pragma unroll
                    for (int r = 0; r < 4; r++) lbuf[m * 16 + quad * 4 + r] = lacc[m][r];
                }
            } else {
#pragma unroll
                for (int m = 0; m < 4; m++) {
#pragma unroll
                    for (int dc8 = 0; dc8 < 8; dc8++)
#pragma unroll
                        for (int r = 0; r < 4; r++)
                            obuf[(m * 16 + quad * 4 + r) * 132 + dc8 * 16 + lc] += o[m][dc8][r];
#pragma unroll
                    for (int r = 0; r < 4; r++) lbuf[m * 16 + quad * 4 + r] += lacc[m][r];
                }
            }
        }
    }
    __syncthreads();

    // cooperative normalize + store: thread -> (row = tid/4, 32 cols)
    int row = tid >> 2;                 // 0..63: head m = row>>4, token off = row&15
    int m = row >> 4;
    int cb = (tid & 3) * 32;
    float inv = 1.0f / lbuf[row];
    int token = qbase + (row & 15);
    size_t base = ((size_t)(b * T_SEQ + token) * NQH + g * 4 + m) * HD + cb;
#pragma unroll
    for (int v4 = 0; v4 < 4; v4++) {
        union { u16 h[8]; uint4 u; } pk;
#pragma unroll
        for (int jj = 0; jj < 8; jj++)
            pk.h[jj] = f2b(obuf[row * 132 + cb + v4 * 8 + jj] * inv);
        *(uint4*)(ctx + base + v4 * 8) = pk.u;
    }
}

extern "C" void kernel_launch(void* const* d_in, const int* in_sizes, int n_in,
                              void* d_out, int out_size, void* d_ws, size_t ws_size,
                              hipStream_t stream) {
    const float* x  = (const float*)d_in[0];
    const float* Wq = (const float*)d_in[1];
    const float* Wk = (const float*)d_in[2];
    const float* Wv = (const float*)d_in[3];
    const float* Wo = (const float*)d_in[4];
    const float* ck = (const float*)d_in[5];
    const float* cv = (const float*)d_in[6];
    const int*   sp = (const int*)d_in[7];

    char* p = (char*)d_ws;
    u16* xb   = (u16*)p;                                  // x bf16 (dead after GEMM1)
    u16* qh   = xb;                                       //   aliased: q_h after GEMM1
    p += (size_t)TOKENS * EMBED * 2;                      // 16 MB
    u16* wqkv = (u16*)p; p += (size_t)QKVN * EMBED * 2;   // 48 MB
    u16* wob  = (u16*)p; p += (size_t)EMBED * EMBED * 2;  // 32 MB
    u16* qkvb = (u16*)p;                                  // 24 MB bf16 (dead after rope+vpack)
    u16* ctx  = qkvb;                                     //   aliased: ctx (16 MB) after vpack
    p += (size_t)TOKENS * QKVN * 2;
    u16* kh   = (u16*)p; p += (size_t)2 * NKVH * SMAX * HD * 2;  // 8 MB
    u16* vt8  = (u16*)p;                                         // 8 MB

    static int gemm_attr = 0;
    if (!gemm_attr) {
        (void)hipFuncSetAttribute(reinterpret_cast<const void*>(&gemm256_kernel),
                                  hipFuncAttributeMaxDynamicSharedMemorySize, 131072);
        (void)hipFuncSetAttribute(reinterpret_cast<const void*>(&gemmko_kernel),
                                  hipFuncAttributeMaxDynamicSharedMemorySize, 98304);
        gemm_attr = 1;
    }

    convert_all_kernel<<<(CSEG4 + 255) / 256, 256, 0, stream>>>(x, Wq, Wk, Wv, Wo, xb, wqkv, wob);
    gemm256_kernel<<<dim3(QKVN / 256, TOKENS / 256), 512, 131072, stream>>>(xb, wqkv, qkvb, QKVN, EMBED);
    cache_prefix_kernel<<<256, 256, 0, stream>>>(ck, cv, sp, kh, vt8);
    rope_qk_kernel<<<TOKENS * 2560 / 256, 256, 0, stream>>>(qkvb, sp, qh, kh);
    vpack_kernel<<<1024, 256, 0, stream>>>(qkvb, sp, vt8);
    attn_kernel<<<1024, 256, 36864, stream>>>(qh, kh, vt8, sp, ctx);
    gemmko_kernel<<<dim3(EMBED / 256, TOKENS / 128), 512, 98304, stream>>>(ctx, wob, (float*)d_out, EMBED, EMBED);
}

// Round 5
// 337.197 us; speedup vs baseline: 1.1986x; 1.1357x over previous
//
#include <hip/hip_runtime.h>
#include <stdint.h>

typedef unsigned short u16;
typedef __attribute__((ext_vector_type(8))) short short8x;   // 8 x bf16 (4 VGPRs)
typedef __attribute__((ext_vector_type(4))) float floatx4;   // MFMA C/D

#define TOKENS 2048   // B*T
#define EMBED  4096
#define QKVN   6144   // 4096 q + 1024 k + 1024 v
#define T_SEQ  1024
#define SMAX   2048   // cache length (2*KV_SEQ_LEN)
#define NQH    32
#define NKVH   8
#define HD     128

// RNE f32 -> bf16 (finite inputs only)
static __device__ __forceinline__ u16 f2b(float f) {
    union { float f; uint32_t u; } v; v.f = f;
    uint32_t r = v.u + 0x7fffu + ((v.u >> 16) & 1u);
    return (u16)(r >> 16);
}
static __device__ __forceinline__ float b2f(u16 h) {
    union { uint32_t u; float f; } v; v.u = ((uint32_t)h) << 16; return v.f;
}

static __device__ __forceinline__ void gload_lds16(const u16* g, u16* l) {
    __builtin_amdgcn_global_load_lds(
        (const __attribute__((address_space(1))) uint32_t*)g,
        (__attribute__((address_space(3))) uint32_t*)l, 16, 0, 0);
}

// ---------------- fused f32 -> bf16 conversion for all 5 inputs ----------------
#define CSEG0 2097152              // x        (2048*4096/4)
#define CSEG1 6291456              // +Wq      (4096*4096/4)
#define CSEG2 7340032              // +Wk      (1024*4096/4)
#define CSEG3 8388608              // +Wv      (1024*4096/4)
#define CSEG4 12582912             // +Wo      (4096*4096/4)
__global__ void convert_all_kernel(const float* __restrict__ x,  const float* __restrict__ Wq,
                                   const float* __restrict__ Wk, const float* __restrict__ Wv,
                                   const float* __restrict__ Wo,
                                   u16* __restrict__ xb, u16* __restrict__ wqkv,
                                   u16* __restrict__ wob) {
    int i = blockIdx.x * blockDim.x + threadIdx.x;   // float4 index
    if (i >= CSEG4) return;
    const float4* src; uint2* dst; int off;
    if (i < CSEG0)      { src = (const float4*)x;  dst = (uint2*)xb;   off = i; }
    else if (i < CSEG1) { src = (const float4*)Wq; dst = (uint2*)wqkv; off = i - CSEG0; }
    else if (i < CSEG2) { src = (const float4*)Wk; dst = (uint2*)wqkv + 4194304; off = i - CSEG1; }
    else if (i < CSEG3) { src = (const float4*)Wv; dst = (uint2*)wqkv + 5242880; off = i - CSEG2; }
    else                { src = (const float4*)Wo; dst = (uint2*)wob;  off = i - CSEG3; }
    float4 f = src[off];
    union { u16 h[4]; uint2 v; } o;
    o.h[0] = f2b(f.x); o.h[1] = f2b(f.y); o.h[2] = f2b(f.z); o.h[3] = f2b(f.w);
    dst[off] = o.v;
}

// ---------------- GEMM1: C[M,N] = A[M,K] * B[N,K]^T, 256x256 tile ----------------
// 8 waves (2M x 4N), per-wave 128x64, BK=64. NEW (AH,kk) phase scheme: per K-tile
// P(A0,k0){af 4 + bf 4 reads} P(A1,k0){af 4, bf HELD} P(A0,k1){4+4} P(A1,k1){4}
// = 24 ds_read_b128/K-tile/wave (minimum) with only bf (16 VGPR) held across ONE
// phase boundary -- af transient, no spill (R3's 64-held-reg variant spilled).
// Ledger: stages in 4-load clumps at P1/P4/P5/P8; vmcnt(4) at P4/P8; each staged
// half-buffer is dead >=1 barrier before its gload issues (liveness-checked).
#define HB(BUF, MAT, H) (lds + (((BUF) * 4 + (MAT) * 2 + (H)) * 8192))
#define STAGE(BUF, MAT, H, KT) do { \
    const u16* _g0 = (MAT) ? gB[H][0] : gA[H][0]; \
    const u16* _g1 = (MAT) ? gB[H][1] : gA[H][1]; \
    gload_lds16(_g0 + (size_t)(KT) * 64, HB(BUF, MAT, H) + dOff0); \
    gload_lds16(_g1 + (size_t)(KT) * 64, HB(BUF, MAT, H) + dOff1); \
} while (0)
#define WAIT4 asm volatile("s_waitcnt vmcnt(4)" ::: "memory")
#define WAIT0 asm volatile("s_waitcnt vmcnt(0)" ::: "memory")
#define NOSTG ((void)0)
#define LDAF(CBUF, AH, KK) do { const u16* _p = HB(CBUF, 0, AH); \
    _Pragma("unroll") \
    for (int _mi = 0; _mi < 4; _mi++) \
        af[_mi] = *(const short8x*)(_p + offA[_mi][KK]); } while (0)
#define LDBF(CBUF, KK) do { \
    const u16* _p0 = HB(CBUF, 1, 0); \
    const u16* _p1 = HB(CBUF, 1, 1); \
    bf[0] = *(const short8x*)(_p0 + offB[0][KK]); \
    bf[1] = *(const short8x*)(_p0 + offB[1][KK]); \
    bf[2] = *(const short8x*)(_p1 + offB[0][KK]); \
    bf[3] = *(const short8x*)(_p1 + offB[1][KK]); } while (0)
#define NOLDB ((void)0)
#define PHASE(CBUF, AH, KK, LOADB, STAGES, ENDW) do { \
    LDAF(CBUF, AH, KK); \
    LOADB; \
    STAGES; \
    __builtin_amdgcn_s_barrier(); \
    asm volatile("s_waitcnt lgkmcnt(0)" ::: "memory"); \
    __builtin_amdgcn_sched_barrier(0); \
    __builtin_amdgcn_s_setprio(1); \
    _Pragma("unroll") \
    for (int _mi = 0; _mi < 4; _mi++) \
        _Pragma("unroll") \
        for (int _nj = 0; _nj < 4; _nj++) \
            acc[AH][_mi][_nj] = __builtin_amdgcn_mfma_f32_16x16x32_bf16( \
                af[_mi], bf[_nj], acc[AH][_mi][_nj], 0, 0, 0); \
    __builtin_amdgcn_s_setprio(0); \
    ENDW; \
    __builtin_amdgcn_s_barrier(); \
    __builtin_amdgcn_sched_barrier(0); \
} while (0)

__global__ __launch_bounds__(512, 1) void gemm256_kernel(
    const u16* __restrict__ A, const u16* __restrict__ Bw,
    u16* __restrict__ Cv, int N, int K) {
    extern __shared__ __align__(16) u16 lds[];   // 128 KiB dynamic
    const int tid = threadIdx.x;
    const int lane = tid & 63, w = tid >> 6;
    const int quad = lane >> 4, lc = lane & 15;
    const int wm = w >> 2, wn = w & 3;           // 2M x 4N wave grid
    const int Mbase = blockIdx.y * 256, Nbase = blockIdx.x * 256;

    // ---- staging addresses: linear LDS dest, swizzled global source ----
    const int r8 = lane >> 3;                    // row within 8-row wave stripe
    const int sl = (lane & 7) ^ r8;              // pre-swizzled 16B slot in row
    const int srow = w * 8 + r8;                 // 0..63 within a 64-row load stripe
    const u16* gA[2][2];                         // [half][load]
    const u16* gB[2][2];
#pragma unroll
    for (int H = 0; H < 2; H++)
#pragma unroll
        for (int L = 0; L < 2; L++) {
            gA[H][L] = A  + (size_t)(Mbase + H * 128 + L * 64 + srow) * K + sl * 8;
            gB[H][L] = Bw + (size_t)(Nbase + H * 128 + L * 64 + srow) * K + sl * 8;
        }
    const int dOff0 = w * 8 * 64;                // wave-uniform LDS dests (u16)
    const int dOff1 = (64 + w * 8) * 64;

    // ---- ds_read offsets (u16) within a 128x64 half-buffer, swizzled ----
    int offA[4][2], offB[2][2];
    const int xsw = lc & 7;
#pragma unroll
    for (int mi = 0; mi < 4; mi++)
#pragma unroll
        for (int kk = 0; kk < 2; kk++)
            offA[mi][kk] = (wm * 64 + mi * 16 + lc) * 64 + (((kk * 4 + quad) ^ xsw) * 8);
#pragma unroll
    for (int ni = 0; ni < 2; ni++)
#pragma unroll
        for (int kk = 0; kk < 2; kk++)
            offB[ni][kk] = (wn * 32 + ni * 16 + lc) * 64 + (((kk * 4 + quad) ^ xsw) * 8);

    floatx4 acc[2][4][4] = {};                   // [AH][mi][nj] (nj: BH=nj>>1, ni=nj&1)
    short8x af[4];                               // transient A fragments (this phase)
    short8x bf[4];                               // B@kk fragments, held across one boundary

    // prologue: tile0 all 4 halves (8 loads), tile1 A0+B0 (4); WAIT4 drains tile0
    STAGE(0, 0, 0, 0);
    STAGE(0, 1, 0, 0);
    STAGE(0, 0, 1, 0);
    STAGE(0, 1, 1, 0);
    STAGE(1, 0, 0, 1);
    STAGE(1, 1, 0, 1);
    WAIT4;
    __builtin_amdgcn_s_barrier();
    __builtin_amdgcn_sched_barrier(0);

    const int NT = K >> 6;                       // 64 for K=4096
    for (int t = 0; t < NT - 2; t += 2) {
        // tile t (buf 0): phases (A0,k0)(A1,k0)(A0,k1)(A1,k1)
        PHASE(0, 0, 0, LDBF(0, 0), STAGE(1, 0, 1, t + 1); STAGE(1, 1, 1, t + 1), NOSTG);
        PHASE(0, 1, 0, NOLDB, NOSTG, NOSTG);
        PHASE(0, 0, 1, LDBF(0, 1), NOSTG, NOSTG);
        PHASE(0, 1, 1, NOLDB, STAGE(0, 0, 0, t + 2); STAGE(0, 1, 0, t + 2), WAIT4);
        // tile t+1 (buf 1)
        PHASE(1, 0, 0, LDBF(1, 0), STAGE(0, 0, 1, t + 2); STAGE(0, 1, 1, t + 2), NOSTG);
        PHASE(1, 1, 0, NOLDB, NOSTG, NOSTG);
        PHASE(1, 0, 1, LDBF(1, 1), NOSTG, NOSTG);
        PHASE(1, 1, 1, NOLDB, STAGE(1, 0, 0, t + 3); STAGE(1, 1, 0, t + 3), WAIT4);
    }
    // peeled last iteration (tiles NT-2, NT-1): stage only A1/B1(NT-1); WAIT0 at P4
    PHASE(0, 0, 0, LDBF(0, 0), STAGE(1, 0, 1, NT - 1); STAGE(1, 1, 1, NT - 1), NOSTG);
    PHASE(0, 1, 0, NOLDB, NOSTG, NOSTG);
    PHASE(0, 0, 1, LDBF(0, 1), NOSTG, NOSTG);
    PHASE(0, 1, 1, NOLDB, NOSTG, WAIT0);
    PHASE(1, 0, 0, LDBF(1, 0), NOSTG, NOSTG);
    PHASE(1, 1, 0, NOLDB, NOSTG, NOSTG);
    PHASE(1, 0, 1, LDBF(1, 1), NOSTG, NOSTG);
    PHASE(1, 1, 1, NOLDB, NOSTG, NOSTG);

    // epilogue C write (C/D layout: col = lane&15, row = quad*4 + r)
#pragma unroll
    for (int AH = 0; AH < 2; AH++)
#pragma unroll
        for (int mi = 0; mi < 4; mi++) {
            const int row0 = Mbase + AH * 128 + wm * 64 + mi * 16 + quad * 4;
#pragma unroll
            for (int nj = 0; nj < 4; nj++) {
                const int col = Nbase + (nj >> 1) * 128 + wn * 32 + (nj & 1) * 16 + lc;
#pragma unroll
                for (int r = 0; r < 4; r++)
                    Cv[(size_t)(row0 + r) * N + col] = f2b(acc[AH][mi][nj][r]);
            }
        }
}
#undef HB
#undef STAGE
#undef LDAF
#undef LDBF
#undef NOLDB
#undef PHASE

// ---------------- GEMM2: C[M,N](f32) = A[M,K] * B[N,K]^T, 128x256 tile ----------------
// (unchanged from R3/R4 -- isolate the gemm256 change this round)
#define HA2(BUF, H) (lds + (BUF) * 24576 + (H) * 4096)
#define HBB2(BUF)   (lds + (BUF) * 24576 + 8192)
#define STGA2(BUF, H, KT) gload_lds16(gA2[H] + (size_t)(KT) * 64, HA2(BUF, H) + dOffW)
#define STGB2(BUF, KT) do { \
    _Pragma("unroll") \
    for (int _L = 0; _L < 4; _L++) \
        gload_lds16(gB2[_L] + (size_t)(KT) * 64, HBB2(BUF) + _L * 4096 + dOffW); \
} while (0)
#define WAIT5 asm volatile("s_waitcnt vmcnt(5)" ::: "memory")
#define LDA2(CBUF, AH) do { const u16* _p = HA2(CBUF, AH); \
    _Pragma("unroll") \
    for (int _mi = 0; _mi < 2; _mi++) { \
        af2[_mi][0] = *(const short8x*)(_p + offA2[_mi][0]); \
        af2[_mi][1] = *(const short8x*)(_p + offA2[_mi][1]); } } while (0)
#define LDB2(CBUF) do { const u16* _p = HBB2(CBUF); \
    _Pragma("unroll") \
    for (int _nj = 0; _nj < 4; _nj++) { \
        bf2[_nj][0] = *(const short8x*)(_p + offB2[_nj][0]); \
        bf2[_nj][1] = *(const short8x*)(_p + offB2[_nj][1]); } } while (0)
#define PHASE2(CBUF, AH, LOADS, STAGES, ENDW) do { \
    LOADS; \
    STAGES; \
    __builtin_amdgcn_s_barrier(); \
    asm volatile("s_waitcnt lgkmcnt(0)" ::: "memory"); \
    __builtin_amdgcn_sched_barrier(0); \
    __builtin_amdgcn_s_setprio(1); \
    _Pragma("unroll") \
    for (int _kk = 0; _kk < 2; _kk++) \
        _Pragma("unroll") \
        for (int _mi = 0; _mi < 2; _mi++) \
            _Pragma("unroll") \
            for (int _nj = 0; _nj < 4; _nj++) \
                acc2[AH][_mi][_nj] = __builtin_amdgcn_mfma_f32_16x16x32_bf16( \
                    af2[_mi][_kk], bf2[_nj][_kk], acc2[AH][_mi][_nj], 0, 0, 0); \
    __builtin_amdgcn_s_setprio(0); \
    ENDW; \
    __builtin_amdgcn_s_barrier(); \
    __builtin_amdgcn_sched_barrier(0); \
} while (0)

__global__ __launch_bounds__(512, 1) void gemmko_kernel(
    const u16* __restrict__ A, const u16* __restrict__ Bw,
    float* __restrict__ C, int N, int K) {
    extern __shared__ __align__(16) u16 lds[];   // 96 KiB dynamic
    const int tid = threadIdx.x;
    const int lane = tid & 63, w = tid >> 6;
    const int quad = lane >> 4, lc = lane & 15;
    const int wm = (w >> 2) & 1, wn = w & 3;     // 2M x 4N wave grid
    const int Mbase = blockIdx.y * 128, Nbase = blockIdx.x * 256;

    const int r8 = lane >> 3;
    const int sl = (lane & 7) ^ r8;              // pre-swizzled 16B slot
    const int srow = w * 8 + r8;                 // 0..63 within a 64-row unit
    const u16* gA2[2];
    const u16* gB2[4];
#pragma unroll
    for (int H = 0; H < 2; H++)
        gA2[H] = A + (size_t)(Mbase + H * 64 + srow) * K + sl * 8;
#pragma unroll
    for (int L = 0; L < 4; L++)
        gB2[L] = Bw + (size_t)(Nbase + L * 64 + srow) * K + sl * 8;
    const int dOffW = w * 512;                   // wave-uniform LDS dest (u16)

    int offA2[2][2], offB2[4][2];
    const int xsw = lc & 7;
#pragma unroll
    for (int mi = 0; mi < 2; mi++)
#pragma unroll
        for (int kk = 0; kk < 2; kk++)
            offA2[mi][kk] = (wm * 32 + mi * 16 + lc) * 64 + (((kk * 4 + quad) ^ xsw) * 8);
#pragma unroll
    for (int nj = 0; nj < 4; nj++)
#pragma unroll
        for (int kk = 0; kk < 2; kk++)
            offB2[nj][kk] = (wn * 64 + nj * 16 + lc) * 64 + (((kk * 4 + quad) ^ xsw) * 8);

    floatx4 acc2[2][2][4] = {};                  // [AH][mi][nj]
    short8x af2[2][2], bf2[4][2];

    // prologue: tile0 fully (6), tile1 A0+B (5); wait drains tile0's 6
    STGA2(0, 0, 0); STGA2(0, 1, 0); STGB2(0, 0);
    STGA2(1, 0, 1); STGB2(1, 1);
    WAIT5;
    __builtin_amdgcn_s_barrier();
    __builtin_amdgcn_sched_barrier(0);

    const int NT = K >> 6;                       // 64
    for (int t = 0; t < NT - 2; t += 2) {
        PHASE2(0, 0, LDA2(0, 0); LDB2(0), STGA2(1, 1, t + 1), NOSTG);
        PHASE2(0, 1, LDA2(0, 1), STGA2(0, 0, t + 2); STGB2(0, t + 2), WAIT5);
        PHASE2(1, 0, LDA2(1, 0); LDB2(1), STGA2(0, 1, t + 2), NOSTG);
        PHASE2(1, 1, LDA2(1, 1), STGA2(1, 0, t + 3); STGB2(1, t + 3), WAIT5);
    }
    PHASE2(0, 0, LDA2(0, 0); LDB2(0), STGA2(1, 1, NT - 1), NOSTG);
    PHASE2(0, 1, LDA2(0, 1), NOSTG, WAIT0);
    PHASE2(1, 0, LDA2(1, 0); LDB2(1), NOSTG, NOSTG);
    PHASE2(1, 1, LDA2(1, 1), NOSTG, NOSTG);

    // epilogue (f32 out)
#pragma unroll
    for (int AH = 0; AH < 2; AH++)
#pragma unroll
        for (int mi = 0; mi < 2; mi++) {
            const int row0 = Mbase + AH * 64 + wm * 32 + mi * 16 + quad * 4;
#pragma unroll
            for (int nj = 0; nj < 4; nj++) {
                const int col = Nbase + wn * 64 + nj * 16 + lc;
#pragma unroll
                for (int r = 0; r < 4; r++)
                    C[(size_t)(row0 + r) * N + col] = acc2[AH][mi][nj][r];
            }
        }
}
#undef HA2
#undef HBB2
#undef STGA2
#undef STGB2
#undef WAIT5
#undef LDA2
#undef LDB2
#undef PHASE2
#undef WAIT4
#undef WAIT0
#undef NOSTG

// ---------------- cache prefix copy (no-op when start_pos==0) ----------------
// kh: (b,g,s,d) row-major. vt8: 8-token interleaved (s>>3)*1024 + d*8 + (s&7).
__global__ void cache_prefix_kernel(const float* __restrict__ ck, const float* __restrict__ cv,
                                    const int* __restrict__ sp,
                                    u16* __restrict__ kh, u16* __restrict__ vt8) {
    int spos = sp[0];
    long total = (long)2 * spos * NKVH * HD;
    for (long i = (long)blockIdx.x * blockDim.x + threadIdx.x; i < total; i += (long)gridDim.x * blockDim.x) {
        long d = i % HD, rest = i / HD;
        long g = rest % NKVH; rest /= NKVH;
        long s = rest % spos; long b = rest / spos;
        float kv = ck[((b * SMAX + s) * NKVH + g) * HD + d];
        kh[((b * NKVH + g) * SMAX + s) * HD + d] = f2b(kv);
        float vv = cv[((b * SMAX + s) * NKVH + g) * HD + d];
        vt8[(size_t)(b * NKVH + g) * SMAX * HD + (s >> 3) * 1024 + d * 8 + (s & 7)] = f2b(vv);
    }
}

// ---------------- RoPE for Q and K (reads bf16 qkv) ----------------
__global__ void rope_qk_kernel(const u16* __restrict__ qkvb, const int* __restrict__ sp,
                               u16* __restrict__ qh, u16* __restrict__ kh) {
    int spos = sp[0];
    int idx = blockIdx.x * blockDim.x + threadIdx.x;   // tok*2560 + u
    int tok = idx / 2560;
    int u = idx - tok * 2560;
    int b = tok >> 10, t = tok & 1023;
    float pos = (float)(spos + t);
    const u16* src = qkvb + (size_t)tok * QKVN;
    const float kScale = 0.08838834764831845f;  // 1/sqrt(128)
    const float kLog = -0.20762050593045857f;   // -log2(10000)/64
    if (u < 2048) {                 // q: 32 heads x 64 pairs
        int h = u >> 6, i = u & 63;
        float ang = pos * exp2f((float)i * kLog);
        float cs = cosf(ang), sn = sinf(ang);
        float x0 = b2f(src[h * HD + 2 * i]), x1 = b2f(src[h * HD + 2 * i + 1]);
        size_t dst = (((size_t)(b * NQH + h) * T_SEQ) + t) * HD + 2 * i;
        qh[dst]     = f2b((x0 * cs - x1 * sn) * kScale);
        qh[dst + 1] = f2b((x0 * sn + x1 * cs) * kScale);
    } else {                        // k: 8 heads x 64 pairs
        int u2 = u - 2048;
        int g = u2 >> 6, i = u2 & 63;
        float ang = pos * exp2f((float)i * kLog);
        float cs = cosf(ang), sn = sinf(ang);
        float x0 = b2f(src[EMBED + g * HD + 2 * i]), x1 = b2f(src[EMBED + g * HD + 2 * i + 1]);
        size_t dst = (((size_t)(b * NKVH + g) * SMAX) + spos + t) * HD + 2 * i;
        kh[dst]     = f2b(x0 * cs - x1 * sn);
        kh[dst + 1] = f2b(x0 * sn + x1 * cs);
    }
}

// ---------------- V pack: bf16 qkv -> 8-token-interleaved vt8 (LDS transpose) ----------------
// Block: one (b, g, 16-token tile). Coalesced reads (256B rows) and writes (1KB waves).
__global__ __launch_bounds__(256) void vpack_kernel(const u16* __restrict__ qkvb,
                                                    const int* __restrict__ sp,
                                                    u16* __restrict__ vt8) {
    __shared__ u16 lds[16 * 136];
    int spos = sp[0];
    int tile = blockIdx.x;          // b*512 + g*64 + t16
    int t16 = tile & 63;
    int g = (tile >> 6) & 7;
    int b = tile >> 9;
    int tok0 = t16 * 16;
    int tid = threadIdx.x;
    {
        int srow = tid >> 4, dc8 = (tid & 15) * 8;
        const u16* src = qkvb + (size_t)(b * T_SEQ + tok0 + srow) * QKVN + 5120 + g * HD + dc8;
        *(uint4*)(lds + srow * 136 + dc8) = *(const uint4*)src;
    }
    __syncthreads();
    int d = tid & 127, half = tid >> 7;
    u16* vpg = vt8 + (size_t)(b * NKVH + g) * SMAX * HD;
    int s0 = spos + tok0;
    u16 val[8];
#pragma unroll
    for (int k = 0; k < 8; k++) val[k] = lds[(half * 8 + k) * 136 + d];
    if ((s0 & 7) == 0) {
        union { u16 h[8]; uint4 u; } pk;
#pragma unroll
        for (int k = 0; k < 8; k++) pk.h[k] = val[k];
        *(uint4*)(vpg + (size_t)((s0 >> 3) + half) * 1024 + d * 8) = pk.u;
    } else {
#pragma unroll
        for (int k = 0; k < 8; k++) {
            int s = s0 + half * 8 + k;
            vpg[(size_t)(s >> 3) * 1024 + d * 8 + (s & 7)] = val[k];
        }
    }
}

// ---------------- causal GQA flash attention v4 ----------------
// Wave M=64 rows = 4 Q-heads (one KV group) x 16 tokens. Block = 4 waves on one
// (b,g,16-token tile), 4-way round-robin key split, fp32 LDS combine. Fixed
// softmax max (m=0); row-sum via ones-B MFMA. V in 8-token-interleaved layout.
// Long causal tiles dispatch first (j reversed) to shrink the tail.
__global__ __launch_bounds__(256, 2) void attn_kernel(
    const u16* __restrict__ qh, const u16* __restrict__ kh,
    const u16* __restrict__ vt8, const int* __restrict__ sp,
    u16* __restrict__ ctx) {
    extern __shared__ __align__(16) char smem[];
    int spos = sp[0];
    int tid = threadIdx.x, w = tid >> 6, lane = tid & 63;
    int quad = lane >> 4, lc = lane & 15;
    int tile = blockIdx.x;          // b*512 + g*64 + (63-j)
    int j = 63 - (tile & 63);       // longest-first dispatch
    int g = (tile >> 6) & 7;
    int b = tile >> 9;
    int qbase = j * 16;

    const u16* kp = kh + (size_t)(b * NKVH + g) * SMAX * HD;
    const u16* vp = vt8 + (size_t)(b * NKVH + g) * SMAX * HD;

    short8x qf[4][4];
#pragma unroll
    for (int m = 0; m < 4; m++) {
        const u16* qp = qh + ((size_t)(b * NQH + g * 4 + m) * T_SEQ + qbase + lc) * HD + quad * 8;
#pragma unroll
        for (int dc = 0; dc < 4; dc++)
            qf[m][dc] = *(const short8x*)(qp + dc * 32);
    }
    short8x ones;
#pragma unroll
    for (int jj = 0; jj < 8; jj++) ones[jj] = (short)0x3F80;   // bf16 1.0

    floatx4 o[4][8] = {};
    floatx4 lacc[4] = {};
    int rowpos = spos + qbase + quad * 4;      // +r = absolute query position
    int nch = (spos + qbase + 16 + 63) >> 6;   // 64-key chunks
    u16* pw = (u16*)smem + w * 4608;           // this wave's P buffer (4 tiles x 16x72)

    for (int c = w; c < nch; c += 4) {
        int koff = c * 64;
#pragma unroll
        for (int st = 0; st < 4; st++) {
            const u16* kr = kp + (size_t)(koff + st * 16 + lc) * HD + quad * 8;
            floatx4 sc[4] = {};
#pragma unroll
            for (int dc = 0; dc < 4; dc++) {
                short8x kf = *(const short8x*)(kr + dc * 32);
#pragma unroll
                for (int m = 0; m < 4; m++)
                    sc[m] = __builtin_amdgcn_mfma_f32_16x16x32_bf16(qf[m][dc], kf, sc[m], 0, 0, 0);
            }
            int skey = koff + st * 16 + lc;
#pragma unroll
            for (int m = 0; m < 4; m++)
#pragma unroll
                for (int r = 0; r < 4; r++) {
                    float p = (skey <= rowpos + r) ? __expf(sc[m][r]) : 0.0f;
                    pw[m * 1152 + (quad * 4 + r) * 72 + st * 16 + lc] = f2b(p);
                }
        }
        asm volatile("s_waitcnt lgkmcnt(0)" ::: "memory");
#pragma unroll
        for (int hf = 0; hf < 2; hf++) {
            short8x pf[4];
#pragma unroll
            for (int m = 0; m < 4; m++)
                pf[m] = *(const short8x*)(pw + m * 1152 + lc * 72 + hf * 32 + quad * 8);
#pragma unroll
            for (int m = 0; m < 4; m++)
                lacc[m] = __builtin_amdgcn_mfma_f32_16x16x32_bf16(pf[m], ones, lacc[m], 0, 0, 0);
            const u16* vbase = vp + ((size_t)koff << 7) + (size_t)(hf * 4 + quad) * 1024 + lc * 8;
#pragma unroll
            for (int dc8 = 0; dc8 < 8; dc8++) {
                short8x vf = *(const short8x*)(vbase + dc8 * 128);
#pragma unroll
                for (int m = 0; m < 4; m++)
                    o[m][dc8] = __builtin_amdgcn_mfma_f32_16x16x32_bf16(pf[m], vf, o[m][dc8], 0, 0, 0);
            }
        }
    }

    // phased fp32 combine across the 4 waves (obuf aliases pbuf -- safe after barrier)
    float* obuf = (float*)smem;                 // 64 x 132
    float* lbuf = (float*)(smem + 33792);       // 64
    for (int ph = 0; ph < 4; ph++) {
        __syncthreads();
        if (w == ph) {
            if (ph == 0) {
#pragma unroll
                for (int m = 0; m < 4; m++) {
#pragma unroll
                    for (int dc8 = 0; dc8 < 8; dc8++)
#pragma unroll
                        for (int r = 0; r < 4; r++)
                            obuf[(m * 16 + quad * 4 + r) * 132 + dc8 * 16 + lc] = o[m][dc8][r];
#pragma unroll
                    for (int r = 0; r < 4; r++) lbuf[m * 16 + quad * 4 + r] = lacc[m][r];
                }
            } else {
#pragma unroll
                for (int m = 0; m < 4; m++) {
#pragma unroll
                    for (int dc8 = 0; dc8 < 8; dc8++)
#pragma unroll
                        for (int r = 0; r < 4; r++)
                            obuf[(m * 16 + quad * 4 + r) * 132 + dc8 * 16 + lc] += o[m][dc8][r];
#pragma unroll
                    for (int r = 0; r < 4; r++) lbuf[m * 16 + quad * 4 + r] += lacc[m][r];
                }
            }
        }
    }
    __syncthreads();

    // cooperative normalize + store: thread -> (row = tid/4, 32 cols)
    int row = tid >> 2;                 // 0..63: head m = row>>4, token off = row&15
    int m = row >> 4;
    int cb = (tid & 3) * 32;
    float inv = 1.0f / lbuf[row];
    int token = qbase + (row & 15);
    size_t base = ((size_t)(b * T_SEQ + token) * NQH + g * 4 + m) * HD + cb;
#pragma unroll
    for (int v4 = 0; v4 < 4; v4++) {
        union { u16 h[8]; uint4 u; } pk;
#pragma unroll
        for (int jj = 0; jj < 8; jj++)
            pk.h[jj] = f2b(obuf[row * 132 + cb + v4 * 8 + jj] * inv);
        *(uint4*)(ctx + base + v4 * 8) = pk.u;
    }
}

extern "C" void kernel_launch(void* const* d_in, const int* in_sizes, int n_in,
                              void* d_out, int out_size, void* d_ws, size_t ws_size,
                              hipStream_t stream) {
    const float* x  = (const float*)d_in[0];
    const float* Wq = (const float*)d_in[1];
    const float* Wk = (const float*)d_in[2];
    const float* Wv = (const float*)d_in[3];
    const float* Wo = (const float*)d_in[4];
    const float* ck = (const float*)d_in[5];
    const float* cv = (const float*)d_in[6];
    const int*   sp = (const int*)d_in[7];

    char* p = (char*)d_ws;
    u16* xb   = (u16*)p;                                  // x bf16 (dead after GEMM1)
    u16* qh   = xb;                                       //   aliased: q_h after GEMM1
    p += (size_t)TOKENS * EMBED * 2;                      // 16 MB
    u16* wqkv = (u16*)p; p += (size_t)QKVN * EMBED * 2;   // 48 MB
    u16* wob  = (u16*)p; p += (size_t)EMBED * EMBED * 2;  // 32 MB
    u16* qkvb = (u16*)p;                                  // 24 MB bf16 (dead after rope+vpack)
    u16* ctx  = qkvb;                                     //   aliased: ctx (16 MB) after vpack
    p += (size_t)TOKENS * QKVN * 2;
    u16* kh   = (u16*)p; p += (size_t)2 * NKVH * SMAX * HD * 2;  // 8 MB
    u16* vt8  = (u16*)p;                                         // 8 MB

    static int gemm_attr = 0;
    if (!gemm_attr) {
        (void)hipFuncSetAttribute(reinterpret_cast<const void*>(&gemm256_kernel),
                                  hipFuncAttributeMaxDynamicSharedMemorySize, 131072);
        (void)hipFuncSetAttribute(reinterpret_cast<const void*>(&gemmko_kernel),
                                  hipFuncAttributeMaxDynamicSharedMemorySize, 98304);
        gemm_attr = 1;
    }

    convert_all_kernel<<<(CSEG4 + 255) / 256, 256, 0, stream>>>(x, Wq, Wk, Wv, Wo, xb, wqkv, wob);
    gemm256_kernel<<<dim3(QKVN / 256, TOKENS / 256), 512, 131072, stream>>>(xb, wqkv, qkvb, QKVN, EMBED);
    cache_prefix_kernel<<<256, 256, 0, stream>>>(ck, cv, sp, kh, vt8);
    rope_qk_kernel<<<TOKENS * 2560 / 256, 256, 0, stream>>>(qkvb, sp, qh, kh);
    vpack_kernel<<<1024, 256, 0, stream>>>(qkvb, sp, vt8);
    attn_kernel<<<1024, 256, 36864, stream>>>(qh, kh, vt8, sp, ctx);
    gemmko_kernel<<<dim3(EMBED / 256, TOKENS / 128), 512, 98304, stream>>>(ctx, wob, (float*)d_out, EMBED, EMBED);
}

// Round 6
// 322.380 us; speedup vs baseline: 1.2536x; 1.0460x over previous
//
#include <hip/hip_runtime.h>
#include <stdint.h>

typedef unsigned short u16;
typedef __attribute__((ext_vector_type(8))) short short8x;   // 8 x bf16 (4 VGPRs)
typedef __attribute__((ext_vector_type(4))) float floatx4;   // MFMA C/D

#define TOKENS 2048   // B*T
#define EMBED  4096
#define QKVN   6144   // 4096 q + 1024 k + 1024 v
#define T_SEQ  1024
#define SMAX   2048   // cache length (2*KV_SEQ_LEN)
#define NQH    32
#define NKVH   8
#define HD     128

// RNE f32 -> bf16 (finite inputs only)
static __device__ __forceinline__ u16 f2b(float f) {
    union { float f; uint32_t u; } v; v.f = f;
    uint32_t r = v.u + 0x7fffu + ((v.u >> 16) & 1u);
    return (u16)(r >> 16);
}
static __device__ __forceinline__ float b2f(u16 h) {
    union { uint32_t u; float f; } v; v.u = ((uint32_t)h) << 16; return v.f;
}

static __device__ __forceinline__ void gload_lds16(const u16* g, u16* l) {
    __builtin_amdgcn_global_load_lds(
        (const __attribute__((address_space(1))) uint32_t*)g,
        (__attribute__((address_space(3))) uint32_t*)l, 16, 0, 0);
}

// ---------------- fused f32 -> bf16 conversion for all 5 inputs ----------------
#define CSEG0 2097152              // x        (2048*4096/4)
#define CSEG1 6291456              // +Wq      (4096*4096/4)
#define CSEG2 7340032              // +Wk      (1024*4096/4)
#define CSEG3 8388608              // +Wv      (1024*4096/4)
#define CSEG4 12582912             // +Wo      (4096*4096/4)
__global__ void convert_all_kernel(const float* __restrict__ x,  const float* __restrict__ Wq,
                                   const float* __restrict__ Wk, const float* __restrict__ Wv,
                                   const float* __restrict__ Wo,
                                   u16* __restrict__ xb, u16* __restrict__ wqkv,
                                   u16* __restrict__ wob) {
    int i = blockIdx.x * blockDim.x + threadIdx.x;   // float4 index
    if (i >= CSEG4) return;
    const float4* src; uint2* dst; int off;
    if (i < CSEG0)      { src = (const float4*)x;  dst = (uint2*)xb;   off = i; }
    else if (i < CSEG1) { src = (const float4*)Wq; dst = (uint2*)wqkv; off = i - CSEG0; }
    else if (i < CSEG2) { src = (const float4*)Wk; dst = (uint2*)wqkv + 4194304; off = i - CSEG1; }
    else if (i < CSEG3) { src = (const float4*)Wv; dst = (uint2*)wqkv + 5242880; off = i - CSEG2; }
    else                { src = (const float4*)Wo; dst = (uint2*)wob;  off = i - CSEG3; }
    float4 f = src[off];
    union { u16 h[4]; uint2 v; } o;
    o.h[0] = f2b(f.x); o.h[1] = f2b(f.y); o.h[2] = f2b(f.z); o.h[3] = f2b(f.w);
    dst[off] = o.v;
}

#define FENCE asm volatile("" ::: "memory")
#define WAIT5 asm volatile("s_waitcnt vmcnt(5)" ::: "memory")
#define WAIT0 asm volatile("s_waitcnt vmcnt(0)" ::: "memory")
#define NOSTG ((void)0)
#define NOLDB ((void)0)

// ---------------- GEMM1: C[M,N] = A[M,K] * B[N,K]^T, 256x192 tile ----------------
// Full-machine grid (32x8 = 256 blocks for 2048x6144). 8 waves (2M x 4N), per-wave
// 128x48. BK=64, 4 phases/K-tile in (AH,kk) scheme: 12 MFMA/phase, 22 ds_read/K-tile,
// bf (3 frags) held across one boundary only. LDS 112 KiB: 2 bufs x {A0,A1 (128x64
// each), B (192x64)}. Barriers use compiler fences only -- ds_reads are C++ loads so
// the compiler emits fine-grained lgkmcnt before MFMAs (no forced full drain).
// Ledger (7 loads/tile: A0=2,A1=2,B=3): A1(t+1)@P1, {A0,B}(t+2)@P4+WAIT5,
// A1(t+2)@P5, {A0,B}(t+3)@P8+WAIT5. Every staged region's last ds_read is >=1
// end-of-phase barrier before its gload (two-barrier phase makes that sufficient).
#define HBA(BUF, H) (lds + (BUF) * 28672 + (H) * 8192)
#define HBB(BUF)    (lds + (BUF) * 28672 + 16384)
#define STGA(BUF, H, KT) do { \
    gload_lds16(gA[H][0] + (size_t)(KT) * 64, HBA(BUF, H) + dOffW); \
    gload_lds16(gA[H][1] + (size_t)(KT) * 64, HBA(BUF, H) + 4096 + dOffW); \
} while (0)
#define STGB(BUF, KT) do { \
    _Pragma("unroll") \
    for (int _L = 0; _L < 3; _L++) \
        gload_lds16(gBv[_L] + (size_t)(KT) * 64, HBB(BUF) + _L * 4096 + dOffW); \
} while (0)
#define LDAF(CBUF, AH, KK) do { const u16* _p = HBA(CBUF, AH); \
    _Pragma("unroll") \
    for (int _mi = 0; _mi < 4; _mi++) \
        af[_mi] = *(const short8x*)(_p + offA[_mi][KK]); } while (0)
#define LDBF(CBUF, KK) do { const u16* _p = HBB(CBUF); \
    _Pragma("unroll") \
    for (int _nj = 0; _nj < 3; _nj++) \
        bf[_nj] = *(const short8x*)(_p + offB[_nj][KK]); } while (0)
#define PHASE(CBUF, AH, KK, LOADB, STAGES, ENDW) do { \
    LDAF(CBUF, AH, KK); \
    LOADB; \
    STAGES; \
    FENCE; __builtin_amdgcn_s_barrier(); FENCE; \
    __builtin_amdgcn_s_setprio(1); \
    _Pragma("unroll") \
    for (int _mi = 0; _mi < 4; _mi++) \
        _Pragma("unroll") \
        for (int _nj = 0; _nj < 3; _nj++) \
            acc[AH][_mi][_nj] = __builtin_amdgcn_mfma_f32_16x16x32_bf16( \
                af[_mi], bf[_nj], acc[AH][_mi][_nj], 0, 0, 0); \
    __builtin_amdgcn_s_setprio(0); \
    ENDW; \
    FENCE; __builtin_amdgcn_s_barrier(); FENCE; \
} while (0)

__global__ __launch_bounds__(512, 1) void gemm256_kernel(
    const u16* __restrict__ A, const u16* __restrict__ Bw,
    u16* __restrict__ Cv, int N, int K) {
    extern __shared__ __align__(16) u16 lds[];   // 112 KiB dynamic
    const int tid = threadIdx.x;
    const int lane = tid & 63, w = tid >> 6;
    const int quad = lane >> 4, lc = lane & 15;
    const int wm = w >> 2, wn = w & 3;           // 2M x 4N wave grid
    const int Mbase = blockIdx.y * 256, Nbase = blockIdx.x * 192;

    // ---- staging addresses: linear LDS dest, swizzled global source ----
    const int r8 = lane >> 3;                    // row within 8-row wave stripe
    const int sl = (lane & 7) ^ r8;              // pre-swizzled 16B slot in row
    const int srow = w * 8 + r8;                 // 0..63 within a 64-row load unit
    const u16* gA[2][2];                         // [half][unit]
    const u16* gBv[3];
#pragma unroll
    for (int H = 0; H < 2; H++)
#pragma unroll
        for (int L = 0; L < 2; L++)
            gA[H][L] = A + (size_t)(Mbase + H * 128 + L * 64 + srow) * K + sl * 8;
#pragma unroll
    for (int L = 0; L < 3; L++)
        gBv[L] = Bw + (size_t)(Nbase + L * 64 + srow) * K + sl * 8;
    const int dOffW = w * 512;                   // wave-uniform LDS dest (u16)

    // ---- ds_read offsets (u16), swizzled ----
    int offA[4][2], offB[3][2];
    const int xsw = lc & 7;
#pragma unroll
    for (int mi = 0; mi < 4; mi++)
#pragma unroll
        for (int kk = 0; kk < 2; kk++)
            offA[mi][kk] = (wm * 64 + mi * 16 + lc) * 64 + (((kk * 4 + quad) ^ xsw) * 8);
#pragma unroll
    for (int nj = 0; nj < 3; nj++)
#pragma unroll
        for (int kk = 0; kk < 2; kk++)
            offB[nj][kk] = (wn * 48 + nj * 16 + lc) * 64 + (((kk * 4 + quad) ^ xsw) * 8);

    floatx4 acc[2][4][3] = {};                   // [AH][mi][nj]
    short8x af[4];                               // transient A fragments
    short8x bf[3];                               // B@kk fragments (held 1 boundary)

    // prologue: tile0 full (7), tile1 A0+B (5); WAIT5 drains tile0
    STGA(0, 0, 0); STGA(0, 1, 0); STGB(0, 0);
    STGA(1, 0, 1); STGB(1, 1);
    WAIT5;
    FENCE; __builtin_amdgcn_s_barrier(); FENCE;

    const int NT = K >> 6;                       // 64 for K=4096
    for (int t = 0; t < NT - 2; t += 2) {
        // tile t (buf 0)
        PHASE(0, 0, 0, LDBF(0, 0), STGA(1, 1, t + 1), NOSTG);
        PHASE(0, 1, 0, NOLDB, NOSTG, NOSTG);
        PHASE(0, 0, 1, LDBF(0, 1), NOSTG, NOSTG);
        PHASE(0, 1, 1, NOLDB, STGA(0, 0, t + 2); STGB(0, t + 2), WAIT5);
        // tile t+1 (buf 1)
        PHASE(1, 0, 0, LDBF(1, 0), STGA(0, 1, t + 2), NOSTG);
        PHASE(1, 1, 0, NOLDB, NOSTG, NOSTG);
        PHASE(1, 0, 1, LDBF(1, 1), NOSTG, NOSTG);
        PHASE(1, 1, 1, NOLDB, STGA(1, 0, t + 3); STGB(1, t + 3), WAIT5);
    }
    // peeled last pair (tiles NT-2, NT-1)
    PHASE(0, 0, 0, LDBF(0, 0), STGA(1, 1, NT - 1), NOSTG);
    PHASE(0, 1, 0, NOLDB, NOSTG, NOSTG);
    PHASE(0, 0, 1, LDBF(0, 1), NOSTG, NOSTG);
    PHASE(0, 1, 1, NOLDB, NOSTG, WAIT0);
    PHASE(1, 0, 0, LDBF(1, 0), NOSTG, NOSTG);
    PHASE(1, 1, 0, NOLDB, NOSTG, NOSTG);
    PHASE(1, 0, 1, LDBF(1, 1), NOSTG, NOSTG);
    PHASE(1, 1, 1, NOLDB, NOSTG, NOSTG);

    // epilogue C write (C/D layout: col = lane&15, row = quad*4 + r)
#pragma unroll
    for (int AH = 0; AH < 2; AH++)
#pragma unroll
        for (int mi = 0; mi < 4; mi++) {
            const int row0 = Mbase + AH * 128 + wm * 64 + mi * 16 + quad * 4;
#pragma unroll
            for (int nj = 0; nj < 3; nj++) {
                const int col = Nbase + wn * 48 + nj * 16 + lc;
#pragma unroll
                for (int r = 0; r < 4; r++)
                    Cv[(size_t)(row0 + r) * N + col] = f2b(acc[AH][mi][nj][r]);
            }
        }
}
#undef HBA
#undef HBB
#undef STGA
#undef STGB
#undef LDAF
#undef LDBF
#undef PHASE

// ---------------- GEMM2: C[M,N](f32) = A[M,K] * B[N,K]^T, 128x256 tile ----------------
// Full-machine grid (16x16=256 blocks). 8 waves, per-wave 64x64. 2 phases/K-tile.
// Same fence-only barrier scheme (compiler-managed lgkmcnt).
#define HA2(BUF, H) (lds + (BUF) * 24576 + (H) * 4096)
#define HBB2(BUF)   (lds + (BUF) * 24576 + 8192)
#define STGA2(BUF, H, KT) gload_lds16(gA2[H] + (size_t)(KT) * 64, HA2(BUF, H) + dOffW)
#define STGB2(BUF, KT) do { \
    _Pragma("unroll") \
    for (int _L = 0; _L < 4; _L++) \
        gload_lds16(gB2[_L] + (size_t)(KT) * 64, HBB2(BUF) + _L * 4096 + dOffW); \
} while (0)
#define WAIT5K asm volatile("s_waitcnt vmcnt(5)" ::: "memory")
#define LDA2(CBUF, AH) do { const u16* _p = HA2(CBUF, AH); \
    _Pragma("unroll") \
    for (int _mi = 0; _mi < 2; _mi++) { \
        af2[_mi][0] = *(const short8x*)(_p + offA2[_mi][0]); \
        af2[_mi][1] = *(const short8x*)(_p + offA2[_mi][1]); } } while (0)
#define LDB2(CBUF) do { const u16* _p = HBB2(CBUF); \
    _Pragma("unroll") \
    for (int _nj = 0; _nj < 4; _nj++) { \
        bf2[_nj][0] = *(const short8x*)(_p + offB2[_nj][0]); \
        bf2[_nj][1] = *(const short8x*)(_p + offB2[_nj][1]); } } while (0)
#define PHASE2(CBUF, AH, LOADS, STAGES, ENDW) do { \
    LOADS; \
    STAGES; \
    FENCE; __builtin_amdgcn_s_barrier(); FENCE; \
    __builtin_amdgcn_s_setprio(1); \
    _Pragma("unroll") \
    for (int _kk = 0; _kk < 2; _kk++) \
        _Pragma("unroll") \
        for (int _mi = 0; _mi < 2; _mi++) \
            _Pragma("unroll") \
            for (int _nj = 0; _nj < 4; _nj++) \
                acc2[AH][_mi][_nj] = __builtin_amdgcn_mfma_f32_16x16x32_bf16( \
                    af2[_mi][_kk], bf2[_nj][_kk], acc2[AH][_mi][_nj], 0, 0, 0); \
    __builtin_amdgcn_s_setprio(0); \
    ENDW; \
    FENCE; __builtin_amdgcn_s_barrier(); FENCE; \
} while (0)

__global__ __launch_bounds__(512, 1) void gemmko_kernel(
    const u16* __restrict__ A, const u16* __restrict__ Bw,
    float* __restrict__ C, int N, int K) {
    extern __shared__ __align__(16) u16 lds[];   // 96 KiB dynamic
    const int tid = threadIdx.x;
    const int lane = tid & 63, w = tid >> 6;
    const int quad = lane >> 4, lc = lane & 15;
    const int wm = (w >> 2) & 1, wn = w & 3;     // 2M x 4N wave grid
    const int Mbase = blockIdx.y * 128, Nbase = blockIdx.x * 256;

    const int r8 = lane >> 3;
    const int sl = (lane & 7) ^ r8;              // pre-swizzled 16B slot
    const int srow = w * 8 + r8;                 // 0..63 within a 64-row unit
    const u16* gA2[2];
    const u16* gB2[4];
#pragma unroll
    for (int H = 0; H < 2; H++)
        gA2[H] = A + (size_t)(Mbase + H * 64 + srow) * K + sl * 8;
#pragma unroll
    for (int L = 0; L < 4; L++)
        gB2[L] = Bw + (size_t)(Nbase + L * 64 + srow) * K + sl * 8;
    const int dOffW = w * 512;                   // wave-uniform LDS dest (u16)

    int offA2[2][2], offB2[4][2];
    const int xsw = lc & 7;
#pragma unroll
    for (int mi = 0; mi < 2; mi++)
#pragma unroll
        for (int kk = 0; kk < 2; kk++)
            offA2[mi][kk] = (wm * 32 + mi * 16 + lc) * 64 + (((kk * 4 + quad) ^ xsw) * 8);
#pragma unroll
    for (int nj = 0; nj < 4; nj++)
#pragma unroll
        for (int kk = 0; kk < 2; kk++)
            offB2[nj][kk] = (wn * 64 + nj * 16 + lc) * 64 + (((kk * 4 + quad) ^ xsw) * 8);

    floatx4 acc2[2][2][4] = {};                  // [AH][mi][nj]
    short8x af2[2][2], bf2[4][2];

    // prologue: tile0 fully (6), tile1 A0+B (5); wait drains tile0's 6
    STGA2(0, 0, 0); STGA2(0, 1, 0); STGB2(0, 0);
    STGA2(1, 0, 1); STGB2(1, 1);
    WAIT5K;
    FENCE; __builtin_amdgcn_s_barrier(); FENCE;

    const int NT = K >> 6;                       // 64
    for (int t = 0; t < NT - 2; t += 2) {
        PHASE2(0, 0, LDA2(0, 0); LDB2(0), STGA2(1, 1, t + 1), NOSTG);
        PHASE2(0, 1, LDA2(0, 1), STGA2(0, 0, t + 2); STGB2(0, t + 2), WAIT5K);
        PHASE2(1, 0, LDA2(1, 0); LDB2(1), STGA2(0, 1, t + 2), NOSTG);
        PHASE2(1, 1, LDA2(1, 1), STGA2(1, 0, t + 3); STGB2(1, t + 3), WAIT5K);
    }
    PHASE2(0, 0, LDA2(0, 0); LDB2(0), STGA2(1, 1, NT - 1), NOSTG);
    PHASE2(0, 1, LDA2(0, 1), NOSTG, WAIT0);
    PHASE2(1, 0, LDA2(1, 0); LDB2(1), NOSTG, NOSTG);
    PHASE2(1, 1, LDA2(1, 1), NOSTG, NOSTG);

    // epilogue (f32 out)
#pragma unroll
    for (int AH = 0; AH < 2; AH++)
#pragma unroll
        for (int mi = 0; mi < 2; mi++) {
            const int row0 = Mbase + AH * 64 + wm * 32 + mi * 16 + quad * 4;
#pragma unroll
            for (int nj = 0; nj < 4; nj++) {
                const int col = Nbase + wn * 64 + nj * 16 + lc;
#pragma unroll
                for (int r = 0; r < 4; r++)
                    C[(size_t)(row0 + r) * N + col] = acc2[AH][mi][nj][r];
            }
        }
}
#undef HA2
#undef HBB2
#undef STGA2
#undef STGB2
#undef WAIT5K
#undef LDA2
#undef LDB2
#undef PHASE2
#undef WAIT5
#undef WAIT0
#undef NOSTG
#undef NOLDB
#undef FENCE

// ---------------- cache prefix copy (no-op when start_pos==0) ----------------
// kh: (b,g,s,d) row-major. vt8: 8-token interleaved (s>>3)*1024 + d*8 + (s&7).
__global__ void cache_prefix_kernel(const float* __restrict__ ck, const float* __restrict__ cv,
                                    const int* __restrict__ sp,
                                    u16* __restrict__ kh, u16* __restrict__ vt8) {
    int spos = sp[0];
    long total = (long)2 * spos * NKVH * HD;
    for (long i = (long)blockIdx.x * blockDim.x + threadIdx.x; i < total; i += (long)gridDim.x * blockDim.x) {
        long d = i % HD, rest = i / HD;
        long g = rest % NKVH; rest /= NKVH;
        long s = rest % spos; long b = rest / spos;
        float kv = ck[((b * SMAX + s) * NKVH + g) * HD + d];
        kh[((b * NKVH + g) * SMAX + s) * HD + d] = f2b(kv);
        float vv = cv[((b * SMAX + s) * NKVH + g) * HD + d];
        vt8[(size_t)(b * NKVH + g) * SMAX * HD + (s >> 3) * 1024 + d * 8 + (s & 7)] = f2b(vv);
    }
}

// ---------------- RoPE for Q and K (reads bf16 qkv) ----------------
__global__ void rope_qk_kernel(const u16* __restrict__ qkvb, const int* __restrict__ sp,
                               u16* __restrict__ qh, u16* __restrict__ kh) {
    int spos = sp[0];
    int idx = blockIdx.x * blockDim.x + threadIdx.x;   // tok*2560 + u
    int tok = idx / 2560;
    int u = idx - tok * 2560;
    int b = tok >> 10, t = tok & 1023;
    float pos = (float)(spos + t);
    const u16* src = qkvb + (size_t)tok * QKVN;
    const float kScale = 0.08838834764831845f;  // 1/sqrt(128)
    const float kLog = -0.20762050593045857f;   // -log2(10000)/64
    if (u < 2048) {                 // q: 32 heads x 64 pairs
        int h = u >> 6, i = u & 63;
        float ang = pos * exp2f((float)i * kLog);
        float cs = cosf(ang), sn = sinf(ang);
        float x0 = b2f(src[h * HD + 2 * i]), x1 = b2f(src[h * HD + 2 * i + 1]);
        size_t dst = (((size_t)(b * NQH + h) * T_SEQ) + t) * HD + 2 * i;
        qh[dst]     = f2b((x0 * cs - x1 * sn) * kScale);
        qh[dst + 1] = f2b((x0 * sn + x1 * cs) * kScale);
    } else {                        // k: 8 heads x 64 pairs
        int u2 = u - 2048;
        int g = u2 >> 6, i = u2 & 63;
        float ang = pos * exp2f((float)i * kLog);
        float cs = cosf(ang), sn = sinf(ang);
        float x0 = b2f(src[EMBED + g * HD + 2 * i]), x1 = b2f(src[EMBED + g * HD + 2 * i + 1]);
        size_t dst = (((size_t)(b * NKVH + g) * SMAX) + spos + t) * HD + 2 * i;
        kh[dst]     = f2b(x0 * cs - x1 * sn);
        kh[dst + 1] = f2b(x0 * sn + x1 * cs);
    }
}

// ---------------- V pack: bf16 qkv -> 8-token-interleaved vt8 (LDS transpose) ----------------
// Block: one (b, g, 16-token tile). Coalesced reads (256B rows) and writes (1KB waves).
__global__ __launch_bounds__(256) void vpack_kernel(const u16* __restrict__ qkvb,
                                                    const int* __restrict__ sp,
                                                    u16* __restrict__ vt8) {
    __shared__ u16 lds[16 * 136];
    int spos = sp[0];
    int tile = blockIdx.x;          // b*512 + g*64 + t16
    int t16 = tile & 63;
    int g = (tile >> 6) & 7;
    int b = tile >> 9;
    int tok0 = t16 * 16;
    int tid = threadIdx.x;
    {
        int srow = tid >> 4, dc8 = (tid & 15) * 8;
        const u16* src = qkvb + (size_t)(b * T_SEQ + tok0 + srow) * QKVN + 5120 + g * HD + dc8;
        *(uint4*)(lds + srow * 136 + dc8) = *(const uint4*)src;
    }
    __syncthreads();
    int d = tid & 127, half = tid >> 7;
    u16* vpg = vt8 + (size_t)(b * NKVH + g) * SMAX * HD;
    int s0 = spos + tok0;
    u16 val[8];
#pragma unroll
    for (int k = 0; k < 8; k++) val[k] = lds[(half * 8 + k) * 136 + d];
    if ((s0 & 7) == 0) {
        union { u16 h[8]; uint4 u; } pk;
#pragma unroll
        for (int k = 0; k < 8; k++) pk.h[k] = val[k];
        *(uint4*)(vpg + (size_t)((s0 >> 3) + half) * 1024 + d * 8) = pk.u;
    } else {
#pragma unroll
        for (int k = 0; k < 8; k++) {
            int s = s0 + half * 8 + k;
            vpg[(size_t)(s >> 3) * 1024 + d * 8 + (s & 7)] = val[k];
        }
    }
}

// ---------------- causal GQA flash attention v4 ----------------
// Wave M=64 rows = 4 Q-heads (one KV group) x 16 tokens. Block = 4 waves on one
// (b,g,16-token tile), 4-way round-robin key split, fp32 LDS combine. Fixed
// softmax max (m=0); row-sum via ones-B MFMA. V in 8-token-interleaved layout.
// Long causal tiles dispatch first (j reversed) to shrink the tail.
__global__ __launch_bounds__(256, 2) void attn_kernel(
    const u16* __restrict__ qh, const u16* __restrict__ kh,
    const u16* __restrict__ vt8, const int* __restrict__ sp,
    u16* __restrict__ ctx) {
    extern __shared__ __align__(16) char smem[];
    int spos = sp[0];
    int tid = threadIdx.x, w = tid >> 6, lane = tid & 63;
    int quad = lane >> 4, lc = lane & 15;
    int tile = blockIdx.x;          // b*512 + g*64 + (63-j)
    int j = 63 - (tile & 63);       // longest-first dispatch
    int g = (tile >> 6) & 7;
    int b = tile >> 9;
    int qbase = j * 16;

    const u16* kp = kh + (size_t)(b * NKVH + g) * SMAX * HD;
    const u16* vp = vt8 + (size_t)(b * NKVH + g) * SMAX * HD;

    short8x qf[4][4];
#pragma unroll
    for (int m = 0; m < 4; m++) {
        const u16* qp = qh + ((size_t)(b * NQH + g * 4 + m) * T_SEQ + qbase + lc) * HD + quad * 8;
#pragma unroll
        for (int dc = 0; dc < 4; dc++)
            qf[m][dc] = *(const short8x*)(qp + dc * 32);
    }
    short8x ones;
#pragma unroll
    for (int jj = 0; jj < 8; jj++) ones[jj] = (short)0x3F80;   // bf16 1.0

    floatx4 o[4][8] = {};
    floatx4 lacc[4] = {};
    int rowpos = spos + qbase + quad * 4;      // +r = absolute query position
    int nch = (spos + qbase + 16 + 63) >> 6;   // 64-key chunks
    u16* pw = (u16*)smem + w * 4608;           // this wave's P buffer (4 tiles x 16x72)

    for (int c = w; c < nch; c += 4) {
        int koff = c * 64;
#pragma unroll
        for (int st = 0; st < 4; st++) {
            const u16* kr = kp + (size_t)(koff + st * 16 + lc) * HD + quad * 8;
            floatx4 sc[4] = {};
#pragma unroll
            for (int dc = 0; dc < 4; dc++) {
                short8x kf = *(const short8x*)(kr + dc * 32);
#pragma unroll
                for (int m = 0; m < 4; m++)
                    sc[m] = __builtin_amdgcn_mfma_f32_16x16x32_bf16(qf[m][dc], kf, sc[m], 0, 0, 0);
            }
            int skey = koff + st * 16 + lc;
#pragma unroll
            for (int m = 0; m < 4; m++)
#pragma unroll
                for (int r = 0; r < 4; r++) {
                    float p = (skey <= rowpos + r) ? __expf(sc[m][r]) : 0.0f;
                    pw[m * 1152 + (quad * 4 + r) * 72 + st * 16 + lc] = f2b(p);
                }
        }
        asm volatile("s_waitcnt lgkmcnt(0)" ::: "memory");
#pragma unroll
        for (int hf = 0; hf < 2; hf++) {
            short8x pf[4];
#pragma unroll
            for (int m = 0; m < 4; m++)
                pf[m] = *(const short8x*)(pw + m * 1152 + lc * 72 + hf * 32 + quad * 8);
#pragma unroll
            for (int m = 0; m < 4; m++)
                lacc[m] = __builtin_amdgcn_mfma_f32_16x16x32_bf16(pf[m], ones, lacc[m], 0, 0, 0);
            const u16* vbase = vp + ((size_t)koff << 7) + (size_t)(hf * 4 + quad) * 1024 + lc * 8;
#pragma unroll
            for (int dc8 = 0; dc8 < 8; dc8++) {
                short8x vf = *(const short8x*)(vbase + dc8 * 128);
#pragma unroll
                for (int m = 0; m < 4; m++)
                    o[m][dc8] = __builtin_amdgcn_mfma_f32_16x16x32_bf16(pf[m], vf, o[m][dc8], 0, 0, 0);
            }
        }
    }

    // phased fp32 combine across the 4 waves (obuf aliases pbuf -- safe after barrier)
    float* obuf = (float*)smem;                 // 64 x 132
    float* lbuf = (float*)(smem + 33792);       // 64
    for (int ph = 0; ph < 4; ph++) {
        __syncthreads();
        if (w == ph) {
            if (ph == 0) {
#pragma unroll
                for (int m = 0; m < 4; m++) {
#pragma unroll
                    for (int dc8 = 0; dc8 < 8; dc8++)
#pragma unroll
                        for (int r = 0; r < 4; r++)
                            obuf[(m * 16 + quad * 4 + r) * 132 + dc8 * 16 + lc] = o[m][dc8][r];
#pragma unroll
                    for (int r = 0; r < 4; r++) lbuf[m * 16 + quad * 4 + r] = lacc[m][r];
                }
            } else {
#pragma unroll
                for (int m = 0; m < 4; m++) {
#pragma unroll
                    for (int dc8 = 0; dc8 < 8; dc8++)
#pragma unroll
                        for (int r = 0; r < 4; r++)
                            obuf[(m * 16 + quad * 4 + r) * 132 + dc8 * 16 + lc] += o[m][dc8][r];
#pragma unroll
                    for (int r = 0; r < 4; r++) lbuf[m * 16 + quad * 4 + r] += lacc[m][r];
                }
            }
        }
    }
    __syncthreads();

    // cooperative normalize + store: thread -> (row = tid/4, 32 cols)
    int row = tid >> 2;                 // 0..63: head m = row>>4, token off = row&15
    int m = row >> 4;
    int cb = (tid & 3) * 32;
    float inv = 1.0f / lbuf[row];
    int token = qbase + (row & 15);
    size_t base = ((size_t)(b * T_SEQ + token) * NQH + g * 4 + m) * HD + cb;
#pragma unroll
    for (int v4 = 0; v4 < 4; v4++) {
        union { u16 h[8]; uint4 u; } pk;
#pragma unroll
        for (int jj = 0; jj < 8; jj++)
            pk.h[jj] = f2b(obuf[row * 132 + cb + v4 * 8 + jj] * inv);
        *(uint4*)(ctx + base + v4 * 8) = pk.u;
    }
}

extern "C" void kernel_launch(void* const* d_in, const int* in_sizes, int n_in,
                              void* d_out, int out_size, void* d_ws, size_t ws_size,
                              hipStream_t stream) {
    const float* x  = (const float*)d_in[0];
    const float* Wq = (const float*)d_in[1];
    const float* Wk = (const float*)d_in[2];
    const float* Wv = (const float*)d_in[3];
    const float* Wo = (const float*)d_in[4];
    const float* ck = (const float*)d_in[5];
    const float* cv = (const float*)d_in[6];
    const int*   sp = (const int*)d_in[7];

    char* p = (char*)d_ws;
    u16* xb   = (u16*)p;                                  // x bf16 (dead after GEMM1)
    u16* qh   = xb;                                       //   aliased: q_h after GEMM1
    p += (size_t)TOKENS * EMBED * 2;                      // 16 MB
    u16* wqkv = (u16*)p; p += (size_t)QKVN * EMBED * 2;   // 48 MB
    u16* wob  = (u16*)p; p += (size_t)EMBED * EMBED * 2;  // 32 MB
    u16* qkvb = (u16*)p;                                  // 24 MB bf16 (dead after rope+vpack)
    u16* ctx  = qkvb;                                     //   aliased: ctx (16 MB) after vpack
    p += (size_t)TOKENS * QKVN * 2;
    u16* kh   = (u16*)p; p += (size_t)2 * NKVH * SMAX * HD * 2;  // 8 MB
    u16* vt8  = (u16*)p;                                         // 8 MB

    static int gemm_attr = 0;
    if (!gemm_attr) {
        (void)hipFuncSetAttribute(reinterpret_cast<const void*>(&gemm256_kernel),
                                  hipFuncAttributeMaxDynamicSharedMemorySize, 114688);
        (void)hipFuncSetAttribute(reinterpret_cast<const void*>(&gemmko_kernel),
                                  hipFuncAttributeMaxDynamicSharedMemorySize, 98304);
        gemm_attr = 1;
    }

    convert_all_kernel<<<(CSEG4 + 255) / 256, 256, 0, stream>>>(x, Wq, Wk, Wv, Wo, xb, wqkv, wob);
    gemm256_kernel<<<dim3(QKVN / 192, TOKENS / 256), 512, 114688, stream>>>(xb, wqkv, qkvb, QKVN, EMBED);
    cache_prefix_kernel<<<256, 256, 0, stream>>>(ck, cv, sp, kh, vt8);
    rope_qk_kernel<<<TOKENS * 2560 / 256, 256, 0, stream>>>(qkvb, sp, qh, kh);
    vpack_kernel<<<1024, 256, 0, stream>>>(qkvb, sp, vt8);
    attn_kernel<<<1024, 256, 36864, stream>>>(qh, kh, vt8, sp, ctx);
    gemmko_kernel<<<dim3(EMBED / 256, TOKENS / 128), 512, 98304, stream>>>(ctx, wob, (float*)d_out, EMBED, EMBED);
}

// Round 7
// 322.096 us; speedup vs baseline: 1.2547x; 1.0009x over previous
//
#include <hip/hip_runtime.h>
#include <stdint.h>

typedef unsigned short u16;
typedef __attribute__((ext_vector_type(8))) short short8x;   // 8 x bf16 (4 VGPRs)
typedef __attribute__((ext_vector_type(4))) float floatx4;   // MFMA C/D

#define TOKENS 2048   // B*T
#define EMBED  4096
#define QKVN   6144   // 4096 q + 1024 k + 1024 v
#define T_SEQ  1024
#define SMAX   2048   // cache length (2*KV_SEQ_LEN)
#define NQH    32
#define NKVH   8
#define HD     128

// RNE f32 -> bf16 (finite inputs only)
static __device__ __forceinline__ u16 f2b(float f) {
    union { float f; uint32_t u; } v; v.f = f;
    uint32_t r = v.u + 0x7fffu + ((v.u >> 16) & 1u);
    return (u16)(r >> 16);
}
static __device__ __forceinline__ float b2f(u16 h) {
    union { uint32_t u; float f; } v; v.u = ((uint32_t)h) << 16; return v.f;
}

static __device__ __forceinline__ void gload_lds16(const u16* g, u16* l) {
    __builtin_amdgcn_global_load_lds(
        (const __attribute__((address_space(1))) uint32_t*)g,
        (__attribute__((address_space(3))) uint32_t*)l, 16, 0, 0);
}

// ---------------- fused f32 -> bf16 conversion for all 5 inputs ----------------
#define CSEG0 2097152              // x        (2048*4096/4)
#define CSEG1 6291456              // +Wq      (4096*4096/4)
#define CSEG2 7340032              // +Wk      (1024*4096/4)
#define CSEG3 8388608              // +Wv      (1024*4096/4)
#define CSEG4 12582912             // +Wo      (4096*4096/4)
__global__ void convert_all_kernel(const float* __restrict__ x,  const float* __restrict__ Wq,
                                   const float* __restrict__ Wk, const float* __restrict__ Wv,
                                   const float* __restrict__ Wo,
                                   u16* __restrict__ xb, u16* __restrict__ wqkv,
                                   u16* __restrict__ wob) {
    int i = blockIdx.x * blockDim.x + threadIdx.x;   // float4 index
    if (i >= CSEG4) return;
    const float4* src; uint2* dst; int off;
    if (i < CSEG0)      { src = (const float4*)x;  dst = (uint2*)xb;   off = i; }
    else if (i < CSEG1) { src = (const float4*)Wq; dst = (uint2*)wqkv; off = i - CSEG0; }
    else if (i < CSEG2) { src = (const float4*)Wk; dst = (uint2*)wqkv + 4194304; off = i - CSEG1; }
    else if (i < CSEG3) { src = (const float4*)Wv; dst = (uint2*)wqkv + 5242880; off = i - CSEG2; }
    else                { src = (const float4*)Wo; dst = (uint2*)wob;  off = i - CSEG3; }
    float4 f = src[off];
    union { u16 h[4]; uint2 v; } o;
    o.h[0] = f2b(f.x); o.h[1] = f2b(f.y); o.h[2] = f2b(f.z); o.h[3] = f2b(f.w);
    dst[off] = o.v;
}

#define FENCE asm volatile("" ::: "memory")
#define WAIT5 asm volatile("s_waitcnt vmcnt(5)" ::: "memory")
#define WAIT0 asm volatile("s_waitcnt vmcnt(0)" ::: "memory")
#define NOSTG ((void)0)
#define NOLDB ((void)0)

// ---------------- GEMM1: C[M,N] = A[M,K] * B[N,K]^T, 256x192 tile ----------------
// Full-machine grid (32x8 = 256 blocks). 8 waves (2M x 4N), per-wave 128x48. BK=64.
// 2 phases/K-tile (R6 had 4): P(A0) reads af(8)+bf(6), 24 MFMA; P(A1) reads af(8),
// REUSES bf, 24 MFMA. Same 22 ds_read/K-tile, HALF the barriers (4/K-tile).
// bf (24 VGPR) held across one boundary; af (32) transient; acc 96 -> ~180 peak, no
// spill at 8 waves/CU. Per-element k-order unchanged (kk0,kk1 ascending tiles).
// Ledger (7 loads/tile: A0=2,A1=2,B=3): A1(t+1)@Q1, {A0,B}(t+2)@Q2+WAIT5,
// A1(t+2)@Q3, {A0,B}(t+3)@Q4+WAIT5. In-flight invariant: 5 at iteration start;
// WAIT5 drains exactly the next tile's 7. WAR: each staged region's last ds_read
// is >=1 end-of-phase barrier before its gload issues.
#define HBA(BUF, H) (lds + (BUF) * 28672 + (H) * 8192)
#define HBB(BUF)    (lds + (BUF) * 28672 + 16384)
#define STGA(BUF, H, KT) do { \
    gload_lds16(gA[H][0] + (size_t)(KT) * 64, HBA(BUF, H) + dOffW); \
    gload_lds16(gA[H][1] + (size_t)(KT) * 64, HBA(BUF, H) + 4096 + dOffW); \
} while (0)
#define STGB(BUF, KT) do { \
    _Pragma("unroll") \
    for (int _L = 0; _L < 3; _L++) \
        gload_lds16(gBv[_L] + (size_t)(KT) * 64, HBB(BUF) + _L * 4096 + dOffW); \
} while (0)
#define LDAF(CBUF, AH) do { const u16* _p = HBA(CBUF, AH); \
    _Pragma("unroll") \
    for (int _mi = 0; _mi < 4; _mi++) { \
        af[_mi][0] = *(const short8x*)(_p + offA[_mi][0]); \
        af[_mi][1] = *(const short8x*)(_p + offA[_mi][1]); } } while (0)
#define LDBF(CBUF) do { const u16* _p = HBB(CBUF); \
    _Pragma("unroll") \
    for (int _nj = 0; _nj < 3; _nj++) { \
        bf[_nj][0] = *(const short8x*)(_p + offB[_nj][0]); \
        bf[_nj][1] = *(const short8x*)(_p + offB[_nj][1]); } } while (0)
#define PHASE(CBUF, AH, LOADB, STAGES, ENDW) do { \
    LDAF(CBUF, AH); \
    LOADB; \
    STAGES; \
    FENCE; __builtin_amdgcn_s_barrier(); FENCE; \
    __builtin_amdgcn_s_setprio(1); \
    _Pragma("unroll") \
    for (int _kk = 0; _kk < 2; _kk++) \
        _Pragma("unroll") \
        for (int _mi = 0; _mi < 4; _mi++) \
            _Pragma("unroll") \
            for (int _nj = 0; _nj < 3; _nj++) \
                acc[AH][_mi][_nj] = __builtin_amdgcn_mfma_f32_16x16x32_bf16( \
                    af[_mi][_kk], bf[_nj][_kk], acc[AH][_mi][_nj], 0, 0, 0); \
    __builtin_amdgcn_s_setprio(0); \
    ENDW; \
    FENCE; __builtin_amdgcn_s_barrier(); FENCE; \
} while (0)

__global__ __launch_bounds__(512, 1) void gemm256_kernel(
    const u16* __restrict__ A, const u16* __restrict__ Bw,
    u16* __restrict__ Cv, int N, int K) {
    extern __shared__ __align__(16) u16 lds[];   // 112 KiB dynamic
    const int tid = threadIdx.x;
    const int lane = tid & 63, w = tid >> 6;
    const int quad = lane >> 4, lc = lane & 15;
    const int wm = w >> 2, wn = w & 3;           // 2M x 4N wave grid
    const int Mbase = blockIdx.y * 256, Nbase = blockIdx.x * 192;

    // ---- staging addresses: linear LDS dest, swizzled global source ----
    const int r8 = lane >> 3;                    // row within 8-row wave stripe
    const int sl = (lane & 7) ^ r8;              // pre-swizzled 16B slot in row
    const int srow = w * 8 + r8;                 // 0..63 within a 64-row load unit
    const u16* gA[2][2];                         // [half][unit]
    const u16* gBv[3];
#pragma unroll
    for (int H = 0; H < 2; H++)
#pragma unroll
        for (int L = 0; L < 2; L++)
            gA[H][L] = A + (size_t)(Mbase + H * 128 + L * 64 + srow) * K + sl * 8;
#pragma unroll
    for (int L = 0; L < 3; L++)
        gBv[L] = Bw + (size_t)(Nbase + L * 64 + srow) * K + sl * 8;
    const int dOffW = w * 512;                   // wave-uniform LDS dest (u16)

    // ---- ds_read offsets (u16), swizzled ----
    int offA[4][2], offB[3][2];
    const int xsw = lc & 7;
#pragma unroll
    for (int mi = 0; mi < 4; mi++)
#pragma unroll
        for (int kk = 0; kk < 2; kk++)
            offA[mi][kk] = (wm * 64 + mi * 16 + lc) * 64 + (((kk * 4 + quad) ^ xsw) * 8);
#pragma unroll
    for (int nj = 0; nj < 3; nj++)
#pragma unroll
        for (int kk = 0; kk < 2; kk++)
            offB[nj][kk] = (wn * 48 + nj * 16 + lc) * 64 + (((kk * 4 + quad) ^ xsw) * 8);

    floatx4 acc[2][4][3] = {};                   // [AH][mi][nj]
    short8x af[4][2];                            // transient A fragments (this phase)
    short8x bf[3][2];                            // B fragments (held 1 boundary)

    // prologue: tile0 full (7), tile1 A0+B (5); WAIT5 drains tile0
    STGA(0, 0, 0); STGA(0, 1, 0); STGB(0, 0);
    STGA(1, 0, 1); STGB(1, 1);
    WAIT5;
    FENCE; __builtin_amdgcn_s_barrier(); FENCE;

    const int NT = K >> 6;                       // 64 for K=4096
    for (int t = 0; t < NT - 2; t += 2) {
        // tile t (buf 0)
        PHASE(0, 0, LDBF(0), STGA(1, 1, t + 1), NOSTG);
        PHASE(0, 1, NOLDB, STGA(0, 0, t + 2); STGB(0, t + 2), WAIT5);
        // tile t+1 (buf 1)
        PHASE(1, 0, LDBF(1), STGA(0, 1, t + 2), NOSTG);
        PHASE(1, 1, NOLDB, STGA(1, 0, t + 3); STGB(1, t + 3), WAIT5);
    }
    // peeled last pair (tiles NT-2, NT-1)
    PHASE(0, 0, LDBF(0), STGA(1, 1, NT - 1), NOSTG);
    PHASE(0, 1, NOLDB, NOSTG, WAIT0);
    PHASE(1, 0, LDBF(1), NOSTG, NOSTG);
    PHASE(1, 1, NOLDB, NOSTG, NOSTG);

    // epilogue C write (C/D layout: col = lane&15, row = quad*4 + r)
#pragma unroll
    for (int AH = 0; AH < 2; AH++)
#pragma unroll
        for (int mi = 0; mi < 4; mi++) {
            const int row0 = Mbase + AH * 128 + wm * 64 + mi * 16 + quad * 4;
#pragma unroll
            for (int nj = 0; nj < 3; nj++) {
                const int col = Nbase + wn * 48 + nj * 16 + lc;
#pragma unroll
                for (int r = 0; r < 4; r++)
                    Cv[(size_t)(row0 + r) * N + col] = f2b(acc[AH][mi][nj][r]);
            }
        }
}
#undef HBA
#undef HBB
#undef STGA
#undef STGB
#undef LDAF
#undef LDBF
#undef PHASE

// ---------------- GEMM2: C[M,N](f32) = A[M,K] * B[N,K]^T, 128x256 tile ----------------
// Full-machine grid (16x16=256 blocks). 8 waves, per-wave 64x64. 2 phases/K-tile.
// Fence-only barrier scheme (compiler-managed lgkmcnt). Unchanged from R6.
#define HA2(BUF, H) (lds + (BUF) * 24576 + (H) * 4096)
#define HBB2(BUF)   (lds + (BUF) * 24576 + 8192)
#define STGA2(BUF, H, KT) gload_lds16(gA2[H] + (size_t)(KT) * 64, HA2(BUF, H) + dOffW)
#define STGB2(BUF, KT) do { \
    _Pragma("unroll") \
    for (int _L = 0; _L < 4; _L++) \
        gload_lds16(gB2[_L] + (size_t)(KT) * 64, HBB2(BUF) + _L * 4096 + dOffW); \
} while (0)
#define WAIT5K asm volatile("s_waitcnt vmcnt(5)" ::: "memory")
#define LDA2(CBUF, AH) do { const u16* _p = HA2(CBUF, AH); \
    _Pragma("unroll") \
    for (int _mi = 0; _mi < 2; _mi++) { \
        af2[_mi][0] = *(const short8x*)(_p + offA2[_mi][0]); \
        af2[_mi][1] = *(const short8x*)(_p + offA2[_mi][1]); } } while (0)
#define LDB2(CBUF) do { const u16* _p = HBB2(CBUF); \
    _Pragma("unroll") \
    for (int _nj = 0; _nj < 4; _nj++) { \
        bf2[_nj][0] = *(const short8x*)(_p + offB2[_nj][0]); \
        bf2[_nj][1] = *(const short8x*)(_p + offB2[_nj][1]); } } while (0)
#define PHASE2(CBUF, AH, LOADS, STAGES, ENDW) do { \
    LOADS; \
    STAGES; \
    FENCE; __builtin_amdgcn_s_barrier(); FENCE; \
    __builtin_amdgcn_s_setprio(1); \
    _Pragma("unroll") \
    for (int _kk = 0; _kk < 2; _kk++) \
        _Pragma("unroll") \
        for (int _mi = 0; _mi < 2; _mi++) \
            _Pragma("unroll") \
            for (int _nj = 0; _nj < 4; _nj++) \
                acc2[AH][_mi][_nj] = __builtin_amdgcn_mfma_f32_16x16x32_bf16( \
                    af2[_mi][_kk], bf2[_nj][_kk], acc2[AH][_mi][_nj], 0, 0, 0); \
    __builtin_amdgcn_s_setprio(0); \
    ENDW; \
    FENCE; __builtin_amdgcn_s_barrier(); FENCE; \
} while (0)

__global__ __launch_bounds__(512, 1) void gemmko_kernel(
    const u16* __restrict__ A, const u16* __restrict__ Bw,
    float* __restrict__ C, int N, int K) {
    extern __shared__ __align__(16) u16 lds[];   // 96 KiB dynamic
    const int tid = threadIdx.x;
    const int lane = tid & 63, w = tid >> 6;
    const int quad = lane >> 4, lc = lane & 15;
    const int wm = (w >> 2) & 1, wn = w & 3;     // 2M x 4N wave grid
    const int Mbase = blockIdx.y * 128, Nbase = blockIdx.x * 256;

    const int r8 = lane >> 3;
    const int sl = (lane & 7) ^ r8;              // pre-swizzled 16B slot
    const int srow = w * 8 + r8;                 // 0..63 within a 64-row unit
    const u16* gA2[2];
    const u16* gB2[4];
#pragma unroll
    for (int H = 0; H < 2; H++)
        gA2[H] = A + (size_t)(Mbase + H * 64 + srow) * K + sl * 8;
#pragma unroll
    for (int L = 0; L < 4; L++)
        gB2[L] = Bw + (size_t)(Nbase + L * 64 + srow) * K + sl * 8;
    const int dOffW = w * 512;                   // wave-uniform LDS dest (u16)

    int offA2[2][2], offB2[4][2];
    const int xsw = lc & 7;
#pragma unroll
    for (int mi = 0; mi < 2; mi++)
#pragma unroll
        for (int kk = 0; kk < 2; kk++)
            offA2[mi][kk] = (wm * 32 + mi * 16 + lc) * 64 + (((kk * 4 + quad) ^ xsw) * 8);
#pragma unroll
    for (int nj = 0; nj < 4; nj++)
#pragma unroll
        for (int kk = 0; kk < 2; kk++)
            offB2[nj][kk] = (wn * 64 + nj * 16 + lc) * 64 + (((kk * 4 + quad) ^ xsw) * 8);

    floatx4 acc2[2][2][4] = {};                  // [AH][mi][nj]
    short8x af2[2][2], bf2[4][2];

    // prologue: tile0 fully (6), tile1 A0+B (5); wait drains tile0's 6
    STGA2(0, 0, 0); STGA2(0, 1, 0); STGB2(0, 0);
    STGA2(1, 0, 1); STGB2(1, 1);
    WAIT5K;
    FENCE; __builtin_amdgcn_s_barrier(); FENCE;

    const int NT = K >> 6;                       // 64
    for (int t = 0; t < NT - 2; t += 2) {
        PHASE2(0, 0, LDA2(0, 0); LDB2(0), STGA2(1, 1, t + 1), NOSTG);
        PHASE2(0, 1, LDA2(0, 1), STGA2(0, 0, t + 2); STGB2(0, t + 2), WAIT5K);
        PHASE2(1, 0, LDA2(1, 0); LDB2(1), STGA2(0, 1, t + 2), NOSTG);
        PHASE2(1, 1, LDA2(1, 1), STGA2(1, 0, t + 3); STGB2(1, t + 3), WAIT5K);
    }
    PHASE2(0, 0, LDA2(0, 0); LDB2(0), STGA2(1, 1, NT - 1), NOSTG);
    PHASE2(0, 1, LDA2(0, 1), NOSTG, WAIT0);
    PHASE2(1, 0, LDA2(1, 0); LDB2(1), NOSTG, NOSTG);
    PHASE2(1, 1, LDA2(1, 1), NOSTG, NOSTG);

    // epilogue (f32 out)
#pragma unroll
    for (int AH = 0; AH < 2; AH++)
#pragma unroll
        for (int mi = 0; mi < 2; mi++) {
            const int row0 = Mbase + AH * 64 + wm * 32 + mi * 16 + quad * 4;
#pragma unroll
            for (int nj = 0; nj < 4; nj++) {
                const int col = Nbase + wn * 64 + nj * 16 + lc;
#pragma unroll
                for (int r = 0; r < 4; r++)
                    C[(size_t)(row0 + r) * N + col] = acc2[AH][mi][nj][r];
            }
        }
}
#undef HA2
#undef HBB2
#undef STGA2
#undef STGB2
#undef WAIT5K
#undef LDA2
#undef LDB2
#undef PHASE2
#undef WAIT5
#undef WAIT0
#undef NOSTG
#undef NOLDB
#undef FENCE

// ---------------- cache prefix copy (no-op when start_pos==0) ----------------
// kh: (b,g,s,d) row-major. vt8: 8-token interleaved (s>>3)*1024 + d*8 + (s&7).
__global__ void cache_prefix_kernel(const float* __restrict__ ck, const float* __restrict__ cv,
                                    const int* __restrict__ sp,
                                    u16* __restrict__ kh, u16* __restrict__ vt8) {
    int spos = sp[0];
    long total = (long)2 * spos * NKVH * HD;
    for (long i = (long)blockIdx.x * blockDim.x + threadIdx.x; i < total; i += (long)gridDim.x * blockDim.x) {
        long d = i % HD, rest = i / HD;
        long g = rest % NKVH; rest /= NKVH;
        long s = rest % spos; long b = rest / spos;
        float kv = ck[((b * SMAX + s) * NKVH + g) * HD + d];
        kh[((b * NKVH + g) * SMAX + s) * HD + d] = f2b(kv);
        float vv = cv[((b * SMAX + s) * NKVH + g) * HD + d];
        vt8[(size_t)(b * NKVH + g) * SMAX * HD + (s >> 3) * 1024 + d * 8 + (s & 7)] = f2b(vv);
    }
}

// ---------------- RoPE for Q and K (reads bf16 qkv) ----------------
__global__ void rope_qk_kernel(const u16* __restrict__ qkvb, const int* __restrict__ sp,
                               u16* __restrict__ qh, u16* __restrict__ kh) {
    int spos = sp[0];
    int idx = blockIdx.x * blockDim.x + threadIdx.x;   // tok*2560 + u
    int tok = idx / 2560;
    int u = idx - tok * 2560;
    int b = tok >> 10, t = tok & 1023;
    float pos = (float)(spos + t);
    const u16* src = qkvb + (size_t)tok * QKVN;
    const float kScale = 0.08838834764831845f;  // 1/sqrt(128)
    const float kLog = -0.20762050593045857f;   // -log2(10000)/64
    if (u < 2048) {                 // q: 32 heads x 64 pairs
        int h = u >> 6, i = u & 63;
        float ang = pos * exp2f((float)i * kLog);
        float cs = cosf(ang), sn = sinf(ang);
        float x0 = b2f(src[h * HD + 2 * i]), x1 = b2f(src[h * HD + 2 * i + 1]);
        size_t dst = (((size_t)(b * NQH + h) * T_SEQ) + t) * HD + 2 * i;
        qh[dst]     = f2b((x0 * cs - x1 * sn) * kScale);
        qh[dst + 1] = f2b((x0 * sn + x1 * cs) * kScale);
    } else {                        // k: 8 heads x 64 pairs
        int u2 = u - 2048;
        int g = u2 >> 6, i = u2 & 63;
        float ang = pos * exp2f((float)i * kLog);
        float cs = cosf(ang), sn = sinf(ang);
        float x0 = b2f(src[EMBED + g * HD + 2 * i]), x1 = b2f(src[EMBED + g * HD + 2 * i + 1]);
        size_t dst = (((size_t)(b * NKVH + g) * SMAX) + spos + t) * HD + 2 * i;
        kh[dst]     = f2b(x0 * cs - x1 * sn);
        kh[dst + 1] = f2b(x0 * sn + x1 * cs);
    }
}

// ---------------- V pack: bf16 qkv -> 8-token-interleaved vt8 (LDS transpose) ----------------
// Block: one (b, g, 16-token tile). Coalesced reads (256B rows) and writes (1KB waves).
__global__ __launch_bounds__(256) void vpack_kernel(const u16* __restrict__ qkvb,
                                                    const int* __restrict__ sp,
                                                    u16* __restrict__ vt8) {
    __shared__ u16 lds[16 * 136];
    int spos = sp[0];
    int tile = blockIdx.x;          // b*512 + g*64 + t16
    int t16 = tile & 63;
    int g = (tile >> 6) & 7;
    int b = tile >> 9;
    int tok0 = t16 * 16;
    int tid = threadIdx.x;
    {
        int srow = tid >> 4, dc8 = (tid & 15) * 8;
        const u16* src = qkvb + (size_t)(b * T_SEQ + tok0 + srow) * QKVN + 5120 + g * HD + dc8;
        *(uint4*)(lds + srow * 136 + dc8) = *(const uint4*)src;
    }
    __syncthreads();
    int d = tid & 127, half = tid >> 7;
    u16* vpg = vt8 + (size_t)(b * NKVH + g) * SMAX * HD;
    int s0 = spos + tok0;
    u16 val[8];
#pragma unroll
    for (int k = 0; k < 8; k++) val[k] = lds[(half * 8 + k) * 136 + d];
    if ((s0 & 7) == 0) {
        union { u16 h[8]; uint4 u; } pk;
#pragma unroll
        for (int k = 0; k < 8; k++) pk.h[k] = val[k];
        *(uint4*)(vpg + (size_t)((s0 >> 3) + half) * 1024 + d * 8) = pk.u;
    } else {
#pragma unroll
        for (int k = 0; k < 8; k++) {
            int s = s0 + half * 8 + k;
            vpg[(size_t)(s >> 3) * 1024 + d * 8 + (s & 7)] = val[k];
        }
    }
}

// ---------------- causal GQA flash attention v4 ----------------
// Wave M=64 rows = 4 Q-heads (one KV group) x 16 tokens. Block = 4 waves on one
// (b,g,16-token tile), 4-way round-robin key split, fp32 LDS combine. Fixed
// softmax max (m=0); row-sum via ones-B MFMA. V in 8-token-interleaved layout.
// Long causal tiles dispatch first (j reversed) to shrink the tail.
__global__ __launch_bounds__(256, 2) void attn_kernel(
    const u16* __restrict__ qh, const u16* __restrict__ kh,
    const u16* __restrict__ vt8, const int* __restrict__ sp,
    u16* __restrict__ ctx) {
    extern __shared__ __align__(16) char smem[];
    int spos = sp[0];
    int tid = threadIdx.x, w = tid >> 6, lane = tid & 63;
    int quad = lane >> 4, lc = lane & 15;
    int tile = blockIdx.x;          // b*512 + g*64 + (63-j)
    int j = 63 - (tile & 63);       // longest-first dispatch
    int g = (tile >> 6) & 7;
    int b = tile >> 9;
    int qbase = j * 16;

    const u16* kp = kh + (size_t)(b * NKVH + g) * SMAX * HD;
    const u16* vp = vt8 + (size_t)(b * NKVH + g) * SMAX * HD;

    short8x qf[4][4];
#pragma unroll
    for (int m = 0; m < 4; m++) {
        const u16* qp = qh + ((size_t)(b * NQH + g * 4 + m) * T_SEQ + qbase + lc) * HD + quad * 8;
#pragma unroll
        for (int dc = 0; dc < 4; dc++)
            qf[m][dc] = *(const short8x*)(qp + dc * 32);
    }
    short8x ones;
#pragma unroll
    for (int jj = 0; jj < 8; jj++) ones[jj] = (short)0x3F80;   // bf16 1.0

    floatx4 o[4][8] = {};
    floatx4 lacc[4] = {};
    int rowpos = spos + qbase + quad * 4;      // +r = absolute query position
    int nch = (spos + qbase + 16 + 63) >> 6;   // 64-key chunks
    u16* pw = (u16*)smem + w * 4608;           // this wave's P buffer (4 tiles x 16x72)

    for (int c = w; c < nch; c += 4) {
        int koff = c * 64;
#pragma unroll
        for (int st = 0; st < 4; st++) {
            const u16* kr = kp + (size_t)(koff + st * 16 + lc) * HD + quad * 8;
            floatx4 sc[4] = {};
#pragma unroll
            for (int dc = 0; dc < 4; dc++) {
                short8x kf = *(const short8x*)(kr + dc * 32);
#pragma unroll
                for (int m = 0; m < 4; m++)
                    sc[m] = __builtin_amdgcn_mfma_f32_16x16x32_bf16(qf[m][dc], kf, sc[m], 0, 0, 0);
            }
            int skey = koff + st * 16 + lc;
#pragma unroll
            for (int m = 0; m < 4; m++)
#pragma unroll
                for (int r = 0; r < 4; r++) {
                    float p = (skey <= rowpos + r) ? __expf(sc[m][r]) : 0.0f;
                    pw[m * 1152 + (quad * 4 + r) * 72 + st * 16 + lc] = f2b(p);
                }
        }
        asm volatile("s_waitcnt lgkmcnt(0)" ::: "memory");
#pragma unroll
        for (int hf = 0; hf < 2; hf++) {
            short8x pf[4];
#pragma unroll
            for (int m = 0; m < 4; m++)
                pf[m] = *(const short8x*)(pw + m * 1152 + lc * 72 + hf * 32 + quad * 8);
#pragma unroll
            for (int m = 0; m < 4; m++)
                lacc[m] = __builtin_amdgcn_mfma_f32_16x16x32_bf16(pf[m], ones, lacc[m], 0, 0, 0);
            const u16* vbase = vp + ((size_t)koff << 7) + (size_t)(hf * 4 + quad) * 1024 + lc * 8;
#pragma unroll
            for (int dc8 = 0; dc8 < 8; dc8++) {
                short8x vf = *(const short8x*)(vbase + dc8 * 128);
#pragma unroll
                for (int m = 0; m < 4; m++)
                    o[m][dc8] = __builtin_amdgcn_mfma_f32_16x16x32_bf16(pf[m], vf, o[m][dc8], 0, 0, 0);
            }
        }
    }

    // phased fp32 combine across the 4 waves (obuf aliases pbuf -- safe after barrier)
    float* obuf = (float*)smem;                 // 64 x 132
    float* lbuf = (float*)(smem + 33792);       // 64
    for (int ph = 0; ph < 4; ph++) {
        __syncthreads();
        if (w == ph) {
            if (ph == 0) {
#pragma unroll
                for (int m = 0; m < 4; m++) {
#pragma unroll
                    for (int dc8 = 0; dc8 < 8; dc8++)
#pragma unroll
                        for (int r = 0; r < 4; r++)
                            obuf[(m * 16 + quad * 4 + r) * 132 + dc8 * 16 + lc] = o[m][dc8][r];
#pragma unroll
                    for (int r = 0; r < 4; r++) lbuf[m * 16 + quad * 4 + r] = lacc[m][r];
                }
            } else {
#pragma unroll
                for (int m = 0; m < 4; m++) {
#pragma unroll
                    for (int dc8 = 0; dc8 < 8; dc8++)
#pragma unroll
                        for (int r = 0; r < 4; r++)
                            obuf[(m * 16 + quad * 4 + r) * 132 + dc8 * 16 + lc] += o[m][dc8][r];
#pragma unroll
                    for (int r = 0; r < 4; r++) lbuf[m * 16 + quad * 4 + r] += lacc[m][r];
                }
            }
        }
    }
    __syncthreads();

    // cooperative normalize + store: thread -> (row = tid/4, 32 cols)
    int row = tid >> 2;                 // 0..63: head m = row>>4, token off = row&15
    int m = row >> 4;
    int cb = (tid & 3) * 32;
    float inv = 1.0f / lbuf[row];
    int token = qbase + (row & 15);
    size_t base = ((size_t)(b * T_SEQ + token) * NQH + g * 4 + m) * HD + cb;
#pragma unroll
    for (int v4 = 0; v4 < 4; v4++) {
        union { u16 h[8]; uint4 u; } pk;
#pragma unroll
        for (int jj = 0; jj < 8; jj++)
            pk.h[jj] = f2b(obuf[row * 132 + cb + v4 * 8 + jj] * inv);
        *(uint4*)(ctx + base + v4 * 8) = pk.u;
    }
}

extern "C" void kernel_launch(void* const* d_in, const int* in_sizes, int n_in,
                              void* d_out, int out_size, void* d_ws, size_t ws_size,
                              hipStream_t stream) {
    const float* x  = (const float*)d_in[0];
    const float* Wq = (const float*)d_in[1];
    const float* Wk = (const float*)d_in[2];
    const float* Wv = (const float*)d_in[3];
    const float* Wo = (const float*)d_in[4];
    const float* ck = (const float*)d_in[5];
    const float* cv = (const float*)d_in[6];
    const int*   sp = (const int*)d_in[7];

    char* p = (char*)d_ws;
    u16* xb   = (u16*)p;                                  // x bf16 (dead after GEMM1)
    u16* qh   = xb;                                       //   aliased: q_h after GEMM1
    p += (size_t)TOKENS * EMBED * 2;                      // 16 MB
    u16* wqkv = (u16*)p; p += (size_t)QKVN * EMBED * 2;   // 48 MB
    u16* wob  = (u16*)p; p += (size_t)EMBED * EMBED * 2;  // 32 MB
    u16* qkvb = (u16*)p;                                  // 24 MB bf16 (dead after rope+vpack)
    u16* ctx  = qkvb;                                     //   aliased: ctx (16 MB) after vpack
    p += (size_t)TOKENS * QKVN * 2;
    u16* kh   = (u16*)p; p += (size_t)2 * NKVH * SMAX * HD * 2;  // 8 MB
    u16* vt8  = (u16*)p;                                         // 8 MB

    static int gemm_attr = 0;
    if (!gemm_attr) {
        (void)hipFuncSetAttribute(reinterpret_cast<const void*>(&gemm256_kernel),
                                  hipFuncAttributeMaxDynamicSharedMemorySize, 114688);
        (void)hipFuncSetAttribute(reinterpret_cast<const void*>(&gemmko_kernel),
                                  hipFuncAttributeMaxDynamicSharedMemorySize, 98304);
        gemm_attr = 1;
    }

    convert_all_kernel<<<(CSEG4 + 255) / 256, 256, 0, stream>>>(x, Wq, Wk, Wv, Wo, xb, wqkv, wob);
    gemm256_kernel<<<dim3(QKVN / 192, TOKENS / 256), 512, 114688, stream>>>(xb, wqkv, qkvb, QKVN, EMBED);
    cache_prefix_kernel<<<256, 256, 0, stream>>>(ck, cv, sp, kh, vt8);
    rope_qk_kernel<<<TOKENS * 2560 / 256, 256, 0, stream>>>(qkvb, sp, qh, kh);
    vpack_kernel<<<1024, 256, 0, stream>>>(qkvb, sp, vt8);
    attn_kernel<<<1024, 256, 36864, stream>>>(qh, kh, vt8, sp, ctx);
    gemmko_kernel<<<dim3(EMBED / 256, TOKENS / 128), 512, 98304, stream>>>(ctx, wob, (float*)d_out, EMBED, EMBED);
}